// Round 4
// baseline (814.769 us; speedup 1.0000x reference)
//
#include <hip/hip_runtime.h>

// ---------------------------------------------------------------------------
// Attention_16698832847178: B=2,S=2048,D=2048,H=16,HD=128,L=10
// R9: GEMM K-loop rewritten A-direct: A fragments loaded global->VGPR
// (double-buffered one K-tile ahead, L1-served), only B staged through LDS
// (64KB dbuf). Removes 80KB/tile of LDS traffic (was the binding resource:
// LDS 2070 cyc vs MFMA 1242 cyc per tile per CU). 3 barriers/tile, counted
// vmcnt(3). rope_pack folded into RoPE epilogue; adapter_kv made atomic-free
// (internal k-loop, no memset). flash unchanged from R8.
// ---------------------------------------------------------------------------

typedef unsigned short ushort_t;
typedef unsigned int uint32;
typedef __attribute__((ext_vector_type(8))) short bf16x8;   // 8 bf16 = 4 VGPRs
typedef __attribute__((ext_vector_type(4))) float f32x4;

__device__ __forceinline__ void async16(void* lds, const void* g) {
  __builtin_amdgcn_global_load_lds((const __attribute__((address_space(1))) void*)g,
                                   (__attribute__((address_space(3))) void*)lds,
                                   16, 0, 0);
}
__device__ __forceinline__ ushort_t f2bf(float f) {
  uint32 u = __float_as_uint(f);
  u += 0x7FFFu + ((u >> 16) & 1u);   // round-to-nearest-even
  return (ushort_t)(u >> 16);
}
__device__ __forceinline__ float bf2f(ushort_t b) {
  return __uint_as_float(((uint32)b) << 16);
}
// value from lane^1 via DPP quad_perm [1,0,3,2] (VALU, no LDS)
__device__ __forceinline__ float dpp_xor1(float v) {
  return __int_as_float(__builtin_amdgcn_update_dpp(
      0, __float_as_int(v), 0xB1, 0xf, 0xf, true));
}
#define DPP_MAX(t, ctrl) \
  t = fmaxf(t, __int_as_float(__builtin_amdgcn_update_dpp( \
      0, __float_as_int(t), (ctrl), 0xf, 0xf, true)))
#define DPP_ADD(t, ctrl) \
  t += __int_as_float(__builtin_amdgcn_update_dpp( \
      0, __float_as_int(t), (ctrl), 0xf, 0xf, true))
__device__ __forceinline__ float rowmax16(float t) {
  DPP_MAX(t, 0xB1);   // xor 1
  DPP_MAX(t, 0x4E);   // xor 2
  t = fmaxf(t, __int_as_float(__builtin_amdgcn_ds_swizzle(
      __float_as_int(t), 0x101F)));                  // xor 4
  DPP_MAX(t, 0x128);  // row_ror:8 -> xor 8 (halves uniform after xor1/2/4)
  return t;
}
__device__ __forceinline__ float rowsum16(float t) {
  DPP_ADD(t, 0xB1);
  DPP_ADD(t, 0x4E);
  t += __int_as_float(__builtin_amdgcn_ds_swizzle(__float_as_int(t), 0x101F));
  DPP_ADD(t, 0x128);
  return t;
}

// ---------------------------------------------------------------------------
// cast x (fp32) -> bf16, 8 elements/thread
__global__ __launch_bounds__(256) void cast_x_kernel(const float* __restrict__ x,
                                                     ushort_t* __restrict__ Xb) {
  size_t i = ((size_t)blockIdx.x * 256 + threadIdx.x) * 8;
  float4 a = *(const float4*)(x + i);
  float4 b = *(const float4*)(x + i + 4);
  uint4 o;
  o.x = (uint32)f2bf(a.x) | ((uint32)f2bf(a.y) << 16);
  o.y = (uint32)f2bf(a.z) | ((uint32)f2bf(a.w) << 16);
  o.z = (uint32)f2bf(b.x) | ((uint32)f2bf(b.y) << 16);
  o.w = (uint32)f2bf(b.z) | ((uint32)f2bf(b.w) << 16);
  *(uint4*)(Xb + i) = o;
}

// ---------------------------------------------------------------------------
// W[k][n] fp32 -> Wt[n][k] bf16 (64x64 tiles), dword stores
__global__ __launch_bounds__(256) void transpose_w_kernel(
    const float* __restrict__ w0, const float* __restrict__ w1,
    const float* __restrict__ w2, const float* __restrict__ w3,
    ushort_t* __restrict__ outBase) {
  const float* W = (blockIdx.z == 0) ? w0 : (blockIdx.z == 1) ? w1
                 : (blockIdx.z == 2) ? w2 : w3;
  ushort_t* Wt = outBase + (size_t)blockIdx.z * 4194304;  // 2048*2048
  __shared__ float L[64][65];
  int t = threadIdx.x, tc = t & 63, tr = t >> 6;
  int k0 = blockIdx.x * 64, n0 = blockIdx.y * 64;
  for (int i = 0; i < 16; ++i) {
    int r = i * 4 + tr;
    L[r][tc] = W[(size_t)(k0 + r) * 2048 + n0 + tc];
  }
  __syncthreads();
  int tr8 = t >> 5, tc2 = t & 31;
  for (int i = 0; i < 8; ++i) {
    int r = i * 8 + tr8;
    uint32 pk = (uint32)f2bf(L[2 * tc2][r]) | ((uint32)f2bf(L[2 * tc2 + 1][r]) << 16);
    *(uint32*)(Wt + (size_t)(n0 + r) * 2048 + k0 + 2 * tc2) = pk;
  }
}

// ---------------------------------------------------------------------------
// adapter projections: ak/av[l][n] = sum_k adapter[l][k] * W[k][n]  (fp32)
// R9: internal k-loop, no atomics, no memset. grid (8,1,2).
__global__ __launch_bounds__(256) void adapter_kv_kernel(
    const float* __restrict__ adapter, const float* __restrict__ wk,
    const float* __restrict__ wv, float* __restrict__ ak, float* __restrict__ av) {
  const float* W = blockIdx.z ? wv : wk;
  float* out = blockIdx.z ? av : ak;
  __shared__ float As[10][128];
  int t = threadIdx.x;
  int n = blockIdx.x * 256 + t;
  float acc[10];
#pragma unroll
  for (int l = 0; l < 10; ++l) acc[l] = 0.f;
  for (int k0 = 0; k0 < 2048; k0 += 128) {
    __syncthreads();
    for (int i = t; i < 1280; i += 256)
      As[i >> 7][i & 127] = adapter[(size_t)(i >> 7) * 2048 + k0 + (i & 127)];
    __syncthreads();
    for (int kk = 0; kk < 128; ++kk) {
      float wv_ = W[(size_t)(k0 + kk) * 2048 + n];
#pragma unroll
      for (int l = 0; l < 10; ++l) acc[l] += As[l][kk] * wv_;
    }
  }
#pragma unroll
  for (int l = 0; l < 10; ++l) out[l * 2048 + n] = acc[l];
}

// ---------------------------------------------------------------------------
// pack ak/av (fp32) into MFMA-fragment-friendly bf16 buffers:
// akb[h][l(16)][d(128)] (l>=10 zero), avb[h][d(128)][l(32)] (l>=10 zero)
__global__ __launch_bounds__(256) void adapter_pack_kernel(
    const float* __restrict__ ak, const float* __restrict__ av,
    ushort_t* __restrict__ akb, ushort_t* __restrict__ avb) {
  int t = blockIdx.x * 256 + threadIdx.x;   // 65536 threads
  if (t < 32768) {
    int h = t >> 11, l = (t >> 7) & 15, d = t & 127;
    akb[t] = (l < 10) ? f2bf(ak[l * 2048 + h * 128 + d]) : (ushort_t)0;
  }
  int h = t >> 12, d = (t >> 5) & 127, l = t & 31;
  avb[t] = (l < 10) ? f2bf(av[l * 2048 + h * 128 + d]) : (ushort_t)0;
}

// ---------------------------------------------------------------------------
// Shared pipelined K-loop, A-direct: 128x256 tile, BK=64, nt=32 (K=2048),
// 512 threads = 8 waves (2M x 4N), per-wave C = 64x64 (acc 4x4).
// A fragments: global->VGPR dwordx4 loads, double-buffered one tile ahead
// (16KB A-tile is L1-resident; 4x wave redundancy absorbed by L1).
// B: staged via global_load_lds into 64KB LDS dbuf (XOR chunk swizzle on
// the global source; reads use chunk ^ (row&7)).
// Per tile: {8 B ds_reads | stage B0(t+1) | load A(t+1)x8 | bar |
//   16 MFMA (m01, consumes ALL bfv -> B(t) retired) | bar |
//   stage B123(t+2) (safe: every wave's B reads complete before its 2nd bar) |
//   16 MFMA (m23) | vmcnt(3) | bar}.
// vmcnt(3): per-tile issue order [B0(t+1), A(t+1)x8, B123(t+2)x3] -> waiting
// to 3 outstanding retires everything tile t+1 needs. vmcnt(0) at t==nt-2.
// ---------------------------------------------------------------------------
#define QK_BARX() asm volatile("s_barrier" ::: "memory")

__device__ __forceinline__ void kloop_128x256(
    char* lds, const ushort_t* __restrict__ A, const ushort_t* __restrict__ Bt,
    size_t bm0, size_t bn0, f32x4 (&acc)[4][4]) {
  const int tid = (int)threadIdx.x;
  const int w = tid >> 6, lane = tid & 63, quad = lane >> 4, l15 = lane & 15;
  const int wr = (w >> 2) * 64, wc = (w & 3) * 64;
  const int nt = 32;
  char* const pB0 = lds;
  char* const pB1 = lds + 32768;
  const ushort_t* aBase = A + (bm0 + wr + l15) * 2048;

#define PBT(T) (((T) & 1) ? pB1 : pB0)
#define SEGB(LDSB, GROW, T)                                                    \
  do {                                                                         \
    int rr_ = w * 8 + (lane >> 3);                                             \
    int cl_ = (lane & 7) ^ (rr_ & 7);                                          \
    async16((LDSB) + w * 1024,                                                 \
            Bt + ((GROW) + (size_t)rr_) * 2048 + (size_t)((T) * 64 + cl_ * 8)); \
  } while (0)
#define ST_B0(T)                                                               \
  do { if ((T) < nt) SEGB(PBT(T), bn0, (T)); } while (0)
#define ST_B123(T)                                                             \
  do { if ((T) < nt) { SEGB(PBT(T) + 8192,  bn0 + 64,  (T));                   \
                       SEGB(PBT(T) + 16384, bn0 + 128, (T));                   \
                       SEGB(PBT(T) + 24576, bn0 + 192, (T)); } } while (0)
#define LD_A(DST, T)                                                           \
  do { if ((T) < nt) {                                                         \
    _Pragma("unroll") for (int ii_ = 0; ii_ < 4; ++ii_)                        \
      _Pragma("unroll") for (int ks_ = 0; ks_ < 2; ++ks_)                      \
        DST[ii_][ks_] = *(const bf16x8*)(aBase + ii_ * 32768 +                 \
                          (size_t)((T) * 64) + (ks_ * 4 + quad) * 8);          \
  } } while (0)

  bf16x8 afA[4][2], afB[4][2];

  // prologue: B tile0 + A tile0 + B123 tile1 in flight
  ST_B0(0); ST_B123(0);
  LD_A(afA, 0);
  ST_B123(1);
  asm volatile("s_waitcnt vmcnt(3)" ::: "memory");
  QK_BARX();

#define TILE(T, CUR, NXT)                                                      \
  do {                                                                         \
    const char* pB = PBT(T);                                                   \
    bf16x8 bfv[4][2];                                                          \
    _Pragma("unroll") for (int j_ = 0; j_ < 4; ++j_) {                         \
      int brow_ = wc + j_ * 16 + l15;                                          \
      _Pragma("unroll") for (int ks_ = 0; ks_ < 2; ++ks_)                      \
        bfv[j_][ks_] = *(const bf16x8*)(pB + brow_ * 128 +                     \
                         (((ks_ * 4 + quad) ^ (brow_ & 7)) * 16));             \
    }                                                                          \
    ST_B0((T) + 1);                                                            \
    LD_A(NXT, (T) + 1);                                                        \
    QK_BARX();                                                                 \
    __builtin_amdgcn_s_setprio(1);                                             \
    _Pragma("unroll") for (int ks_ = 0; ks_ < 2; ++ks_)                        \
      _Pragma("unroll") for (int ii_ = 0; ii_ < 2; ++ii_)                      \
        _Pragma("unroll") for (int j_ = 0; j_ < 4; ++j_)                       \
          acc[ii_][j_] = __builtin_amdgcn_mfma_f32_16x16x32_bf16(              \
              CUR[ii_][ks_], bfv[j_][ks_], acc[ii_][j_], 0, 0, 0);             \
    __builtin_amdgcn_s_setprio(0);                                             \
    QK_BARX();                                                                 \
    ST_B123((T) + 2);                                                          \
    __builtin_amdgcn_s_setprio(1);                                             \
    _Pragma("unroll") for (int ks_ = 0; ks_ < 2; ++ks_)                        \
      _Pragma("unroll") for (int ii_ = 2; ii_ < 4; ++ii_)                      \
        _Pragma("unroll") for (int j_ = 0; j_ < 4; ++j_)                       \
          acc[ii_][j_] = __builtin_amdgcn_mfma_f32_16x16x32_bf16(              \
              CUR[ii_][ks_], bfv[j_][ks_], acc[ii_][j_], 0, 0, 0);             \
    __builtin_amdgcn_s_setprio(0);                                             \
    if ((T) == nt - 2) asm volatile("s_waitcnt vmcnt(0)" ::: "memory");        \
    else               asm volatile("s_waitcnt vmcnt(3)" ::: "memory");        \
    QK_BARX();                                                                 \
  } while (0)

  for (int t = 0; t < nt; t += 2) {
    TILE(t, afA, afB);
    TILE(t + 1, afB, afA);
  }
#undef TILE
#undef LD_A
#undef ST_B0
#undef ST_B123
#undef SEGB
#undef PBT
}

// ---------------------------------------------------------------------------
// Fused QKV GEMM: C[4096,6144] = Xb[4096,2048] x WtQKV[6144,2048]^T.
// Grid 768 (32 M x 24 N) = exactly 3 rounds of 256 CUs.
__global__ __launch_bounds__(512, 2) void gemm_qkv128_kernel(
    const ushort_t* __restrict__ A, const ushort_t* __restrict__ Bt,
    ushort_t* __restrict__ outQ, ushort_t* __restrict__ outK,
    ushort_t* __restrict__ Vt,
    const float* __restrict__ fc, const float* __restrict__ fs) {
  __shared__ char lds[65536];
  const int tid = (int)threadIdx.x;
  const int w = tid >> 6, lane = tid & 63, quad = lane >> 4, l15 = lane & 15;
  const int wr = (w >> 2) * 64, wc = (w & 3) * 64;

  const int wg = ((int)blockIdx.x & 7) * 96 + ((int)blockIdx.x >> 3);
  const size_t bm0 = (size_t)(wg & 31) * 128;
  const size_t bn0 = (size_t)(wg >> 5) * 256;

  f32x4 acc[4][4];
  f32x4 z4 = {0.f, 0.f, 0.f, 0.f};
#pragma unroll
  for (int i = 0; i < 4; ++i)
#pragma unroll
    for (int j = 0; j < 4; ++j) acc[i][j] = z4;

  kloop_128x256(lds, A, Bt, bm0, bn0, acc);

  const int seg = (int)(bn0 >> 11);   // 0=Q, 1=K, 2=V
  if (seg < 2) {
    ushort_t* ob = seg ? outK : outQ;
#pragma unroll
    for (int i = 0; i < 4; ++i)
#pragma unroll
      for (int r = 0; r < 4; ++r) {
        size_t m = bm0 + wr + i * 16 + quad * 4 + r;
        int s = (int)(m & 2047);
#pragma unroll
        for (int j = 0; j < 4; ++j) {
          size_t n = (bn0 + wc + j * 16 + l15) & 2047;
          float v = acc[i][j][r];
          float v2 = dpp_xor1(v);             // RoPE pair partner (col n^1)
          int fi = ((int)n & 127) >> 1;
          float cosv = fc[s * 64 + fi];
          float sinv = fs[s * 64 + fi];
          v = (lane & 1) ? (v2 * sinv + v * cosv) : (v * cosv - v2 * sinv);
          ob[m * 2048 + n] = f2bf(v);
        }
      }
  } else {
    // V segment: per-wave 64(n) x 64(m) transpose patch through LDS.
    char* T = lds + w * 8192;
#pragma unroll
    for (int i = 0; i < 4; ++i)
#pragma unroll
      for (int j = 0; j < 4; ++j) {
        int nn = j * 16 + l15;
        int md0 = i * 8 + quad * 2;
        uint32 p01 = (uint32)f2bf(acc[i][j][0]) | ((uint32)f2bf(acc[i][j][1]) << 16);
        uint32 p23 = (uint32)f2bf(acc[i][j][2]) | ((uint32)f2bf(acc[i][j][3]) << 16);
        *(uint32*)(T + nn * 128 + ((md0 ^ (nn & 31)) * 4)) = p01;
        *(uint32*)(T + nn * 128 + (((md0 + 1) ^ (nn & 31)) * 4)) = p23;
      }
    const int b = (int)(bm0 >> 11);
    const int s0 = (int)(bm0 & 2047) + wr;
    const int n2 = (int)(bn0 & 2047) + wc;
#pragma unroll
    for (int it = 0; it < 32; ++it) {
      int row = it * 2 + (lane >> 5);
      int pp = lane & 31;
      uint32 dv = *(const uint32*)(T + row * 128 + pp * 4);
      int md = pp ^ (row & 31);
      int nloc = n2 + row;
      size_t bh = (size_t)b * 16 + (nloc >> 7);
      *(uint32*)(Vt + (bh * 128 + (size_t)(nloc & 127)) * 2048 + s0 + 2 * md) = dv;
    }
  }
}

// ---------------------------------------------------------------------------
// Output projection on the same K-loop: out[4096,2048] fp32 = Ob x WtO^T.
__global__ __launch_bounds__(512, 2) void gemm_wo_kernel(
    const ushort_t* __restrict__ A, const ushort_t* __restrict__ Bt,
    float* __restrict__ out) {
  __shared__ char lds[65536];
  const int tid = (int)threadIdx.x;
  const int w = tid >> 6, lane = tid & 63, quad = lane >> 4, l15 = lane & 15;
  const int wr = (w >> 2) * 64, wc = (w & 3) * 64;

  const int wg = ((int)blockIdx.x & 7) * 32 + ((int)blockIdx.x >> 3);
  const size_t bm0 = (size_t)(wg & 31) * 128;
  const size_t bn0 = (size_t)(wg >> 5) * 256;

  f32x4 acc[4][4];
  f32x4 z4 = {0.f, 0.f, 0.f, 0.f};
#pragma unroll
  for (int i = 0; i < 4; ++i)
#pragma unroll
    for (int j = 0; j < 4; ++j) acc[i][j] = z4;

  kloop_128x256(lds, A, Bt, bm0, bn0, acc);

#pragma unroll
  for (int i = 0; i < 4; ++i)
#pragma unroll
    for (int r = 0; r < 4; ++r) {
      size_t m = bm0 + wr + i * 16 + quad * 4 + r;
#pragma unroll
      for (int j = 0; j < 4; ++j) {
        size_t n = bn0 + wc + j * 16 + l15;
        out[m * 2048 + n] = acc[i][j][r];
      }
    }
}

// ---------------------------------------------------------------------------
// Flash attention, causal, + fused adapter attention. (R8 structure.)
__global__ __launch_bounds__(256, 4) void flash_kernel(
    const ushort_t* __restrict__ Qb, const ushort_t* __restrict__ Kb,
    const ushort_t* __restrict__ Vt, const ushort_t* __restrict__ akb,
    const ushort_t* __restrict__ avb, const float* __restrict__ gate,
    ushort_t* __restrict__ Ob) {
  __shared__ char ldsK[16384];   // 64 tok x 256B, chunk swz ^(row&15)
  __shared__ char ldsV[16384];   // 128 d x 128B, chunk swz ^(dr&7)
  __shared__ char ldsP[8192];    // loop: P 64q x 128B swz; epilogue: pa[64][40]
  const int tid = threadIdx.x;
  const int w = tid >> 6, lane = tid & 63, quad = lane >> 4, l15 = lane & 15;
  const int idx = blockIdx.x;
  const int pg = idx >> 8, c = idx & 255;
  const int u = c >> 3, vv = c & 7;
  const int uu = (pg & 2) ? ((u + 16) & 31) : u;
  const int qt2 = (pg & 1) ? (31 - uu) : uu;     // 64-row q-tile index [0,32)
  const int hb = (pg << 3) | vv;                 // [0,32)
  const int h = hb >> 1, b = hb & 1;
  const float scale = 0.08838834764831845f;      // 1/sqrt(128)

  bf16x8 ones;
#pragma unroll
  for (int j = 0; j < 8; ++j) ones[j] = (short)0x3F80;

  // Q fragments in registers: wave rows w*16..w*16+15, 4 d-steps
  bf16x8 qf[4];
  {
    size_t qrow = (size_t)qt2 * 64 + w * 16 + l15;
    const ushort_t* base = Qb + ((size_t)b * 2048 + qrow) * 2048 + h * 128 + quad * 8;
#pragma unroll
    for (int ds = 0; ds < 4; ++ds) qf[ds] = *(const bf16x8*)(base + ds * 32);
  }

  f32x4 zero4 = {0.f, 0.f, 0.f, 0.f};
  f32x4 oacc[8];
  f32x4 osum = zero4;
  float mrow[4];
#pragma unroll
  for (int n8 = 0; n8 < 8; ++n8) oacc[n8] = zero4;
#pragma unroll
  for (int r = 0; r < 4; ++r) mrow[r] = -1e30f;

  for (int kt = 0; kt <= qt2; ++kt) {
#pragma unroll
    for (int ii = 0; ii < 4; ++ii) {
      int r0 = w * 16 + ii * 4;
      int row = r0 + (lane >> 4);
      int cl = (lane & 15) ^ (row & 15);
      async16(ldsK + r0 * 256,
              Kb + ((size_t)b * 2048 + kt * 64 + row) * 2048 + h * 128 + cl * 8);
    }
#pragma unroll
    for (int ii = 0; ii < 4; ++ii) {
      int d0 = w * 32 + ii * 8;
      int dr = d0 + (lane >> 3);
      int cl = (lane & 7) ^ (dr & 7);
      async16(ldsV + d0 * 128,
              Vt + ((size_t)(b * 16 + h) * 128 + dr) * 2048 + kt * 64 + cl * 8);
    }
    __syncthreads();

    // S = Q K^T
    f32x4 sacc[4];
#pragma unroll
    for (int nt = 0; nt < 4; ++nt) sacc[nt] = zero4;
#pragma unroll
    for (int ds = 0; ds < 4; ++ds) {
      bf16x8 kf[4];
      int ch = ds * 4 + quad;
#pragma unroll
      for (int nt = 0; nt < 4; ++nt) {
        int row = nt * 16 + l15;
        kf[nt] = *(const bf16x8*)(ldsK + row * 256 + ((ch ^ (row & 15)) * 16));
      }
#pragma unroll
      for (int nt = 0; nt < 4; ++nt)
        sacc[nt] = __builtin_amdgcn_mfma_f32_16x16x32_bf16(qf[ds], kf[nt], sacc[nt], 0, 0, 0);
    }

    // online softmax (defer-max, THR=8)
    const bool domask = (kt == qt2);
    float tmax[4] = {-1e30f, -1e30f, -1e30f, -1e30f};
    const int qbr = qt2 * 64 + w * 16 + quad * 4;
#pragma unroll
    for (int nt = 0; nt < 4; ++nt) {
      int kg = kt * 64 + nt * 16 + l15;
#pragma unroll
      for (int r = 0; r < 4; ++r) {
        float s = sacc[nt][r] * scale;
        if (domask && kg > qbr + r) s = -1e30f;
        sacc[nt][r] = s;
        tmax[r] = fmaxf(tmax[r], s);
      }
    }
    float need = 0.f;
#pragma unroll
    for (int r = 0; r < 4; ++r) {
      tmax[r] = rowmax16(tmax[r]);
      need = fmaxf(need, tmax[r] - mrow[r]);
    }
    if (__any(need > 8.0f)) {
      float alpha[4];
#pragma unroll
      for (int r = 0; r < 4; ++r) {
        float mnew = fmaxf(mrow[r], tmax[r]);
        alpha[r] = __expf(mrow[r] - mnew);
        osum[r] *= alpha[r];
        mrow[r] = mnew;
      }
#pragma unroll
      for (int n8 = 0; n8 < 8; ++n8)
#pragma unroll
        for (int r = 0; r < 4; ++r) oacc[n8][r] *= alpha[r];
    }
    uint32 pk[4][4];
#pragma unroll
    for (int nt = 0; nt < 4; ++nt)
#pragma unroll
      for (int r = 0; r < 4; ++r) {
        float pv = __expf(sacc[nt][r] - mrow[r]);
        float pn = dpp_xor1(pv);
        uint32 d_;
        asm volatile("v_cvt_pk_bf16_f32 %0, %1, %2" : "=v"(d_) : "v"(pv), "v"(pn));
        pk[nt][r] = d_;
      }
    if (!(lane & 1)) {
#pragma unroll
      for (int nt = 0; nt < 4; ++nt)
#pragma unroll
        for (int r = 0; r < 4; ++r) {
          int col = nt * 16 + l15;   // even
          int prow = w * 16 + quad * 4 + r;
          *(uint32*)(ldsP + prow * 128 + (((col >> 3) ^ (prow & 7)) * 16) + (col & 7) * 2) = pk[nt][r];
        }
    }

    // O += P V ; osum += P 1
#pragma unroll
    for (int ks = 0; ks < 2; ++ks) {
      int ch = ks * 4 + quad;
      int prow = w * 16 + l15;
      bf16x8 pf = *(const bf16x8*)(ldsP + prow * 128 + ((ch ^ (prow & 7)) * 16));
      osum = __builtin_amdgcn_mfma_f32_16x16x32_bf16(pf, ones, osum, 0, 0, 0);
#pragma unroll
      for (int n8 = 0; n8 < 8; ++n8) {
        int dr = n8 * 16 + l15;
        bf16x8 vf = *(const bf16x8*)(ldsV + dr * 128 + ((ch ^ (dr & 7)) * 16));
        oacc[n8] = __builtin_amdgcn_mfma_f32_16x16x32_bf16(pf, vf, oacc[n8], 0, 0, 0);
      }
    }
    __syncthreads();
  }

  // ---------------- fused adapter epilogue ----------------
  const float g = gate[h];
  {
    int row = w * 16 + (lane >> 2);          // wave's own 16 rows
    *(uint2*)(ldsP + row * 80 + 32 + (lane & 3) * 8) = make_uint2(0, 0);
  }
  f32x4 sa = zero4;
#pragma unroll
  for (int ds = 0; ds < 4; ++ds) {
    bf16x8 kfa = *(const bf16x8*)(akb + ((size_t)h * 16 + l15) * 128 + ds * 32 + quad * 8);
    sa = __builtin_amdgcn_mfma_f32_16x16x32_bf16(qf[ds], kfa, sa, 0, 0, 0);
  }
#pragma unroll
  for (int r = 0; r < 4; ++r) {
    float s = sa[r] * scale;
    if (l15 >= 10) s = -1e30f;
    float mx = rowmax16(s);
    float e = __expf(s - mx);
    float sum = rowsum16(e);
    float pv = g * e / sum;
    int row = w * 16 + quad * 4 + r;
    *(ushort_t*)(ldsP + row * 80 + l15 * 2) = f2bf(pv);
  }
  bf16x8 paf = *(const bf16x8*)(ldsP + (w * 16 + l15) * 80 + quad * 16);

  // normalize main attention
  float rl[4];
#pragma unroll
  for (int r = 0; r < 4; ++r) rl[r] = 1.f / osum[r];
#pragma unroll
  for (int n8 = 0; n8 < 8; ++n8)
#pragma unroll
    for (int r = 0; r < 4; ++r) oacc[n8][r] *= rl[r];
  // += pa @ avb ; store bf16
#pragma unroll
  for (int n8 = 0; n8 < 8; ++n8) {
    bf16x8 avf = *(const bf16x8*)(avb + ((size_t)h * 128 + n8 * 16 + l15) * 32 + quad * 8);
    oacc[n8] = __builtin_amdgcn_mfma_f32_16x16x32_bf16(paf, avf, oacc[n8], 0, 0, 0);
  }
  size_t qb0 = (size_t)qt2 * 64 + w * 16 + quad * 4;
#pragma unroll
  for (int n8 = 0; n8 < 8; ++n8) {
    size_t col = (size_t)h * 128 + n8 * 16 + l15;
#pragma unroll
    for (int r = 0; r < 4; ++r)
      Ob[((size_t)b * 2048 + qb0 + r) * 2048 + col] = f2bf(oacc[n8][r]);
  }
}

// ---------------------------------------------------------------------------
extern "C" void kernel_launch(void* const* d_in, const int* in_sizes, int n_in,
                              void* d_out, int out_size, void* d_ws, size_t ws_size,
                              hipStream_t stream) {
  (void)in_sizes; (void)n_in; (void)out_size; (void)ws_size;
  const float* x       = (const float*)d_in[0];
  const float* wq      = (const float*)d_in[1];
  const float* wk      = (const float*)d_in[2];
  const float* wv      = (const float*)d_in[3];
  const float* wo      = (const float*)d_in[4];
  const float* adapter = (const float*)d_in[5];
  const float* gate    = (const float*)d_in[6];
  const float* fc      = (const float*)d_in[7];
  const float* fs      = (const float*)d_in[8];

  char* ws = (char*)d_ws;
  ushort_t* Xb   = (ushort_t*)(ws + 0);           // 16 MB (reused as Ob)
  ushort_t* WtQ  = (ushort_t*)(ws + 16777216);    // 8 MB x4 contiguous
  ushort_t* WtO  = (ushort_t*)(ws + 41943040);
  ushort_t* Qb   = (ushort_t*)(ws + 50331648);    // 16 MB
  ushort_t* Kb   = (ushort_t*)(ws + 67108864);    // 16 MB
  ushort_t* Vt   = (ushort_t*)(ws + 83886080);    // 16 MB
  float*    ak   = (float*)   (ws + 100663296);   // 80 KB
  float*    av   = (float*)   (ws + 100745216);   // 80 KB
  ushort_t* akb  = (ushort_t*)(ws + 100827136);   // 64 KB
  ushort_t* avb  = (ushort_t*)(ws + 100892672);   // 128 KB
  ushort_t* Ob   = Xb;

  cast_x_kernel<<<4096, 256, 0, stream>>>(x, Xb);
  transpose_w_kernel<<<dim3(32, 32, 4), 256, 0, stream>>>(wq, wk, wv, wo, WtQ);
  adapter_kv_kernel<<<dim3(8, 1, 2), 256, 0, stream>>>(adapter, wk, wv, ak, av);
  adapter_pack_kernel<<<256, 256, 0, stream>>>(ak, av, akb, avb);
  gemm_qkv128_kernel<<<dim3(768), 512, 0, stream>>>(Xb, WtQ, Qb, Kb, Vt, fc, fs);
  flash_kernel<<<dim3(1024), 256, 0, stream>>>(Qb, Kb, Vt, akb, avb, gate, Ob);
  gemm_wo_kernel<<<dim3(256), 512, 0, stream>>>(Ob, WtO, (float*)d_out);
}

// Round 5
// 454.818 us; speedup vs baseline: 1.7914x; 1.7914x over previous
//
#include <hip/hip_runtime.h>

// ---------------------------------------------------------------------------
// Attention_16698832847178: B=2,S=2048,D=2048,H=16,HD=128,L=10
// R10: revert R9's A-direct (L2-thrash, 2.1x regression). QKV GEMM ported to
// 256x256 tile, m201-style 4-phase-per-K-tile schedule: 8 waves (2Mx4N),
// per-wave C=128x64 (acc 8x4), BK=64 K-halved staging, 128KB LDS dbuf,
// counted vmcnt(4), setprio, XOR-swizzled chunks (pre-swizzled global src).
// 1.38x better FLOP/LDS-byte than the 128x256 loop (which is ~80% LDS-busy).
// wo stays on R8's proven 128x256 A-in-LDS kloop. adapter_kv reverted to the
// atomic 256-block version. flash unchanged (R8). RoPE fold kept.
// ---------------------------------------------------------------------------

typedef unsigned short ushort_t;
typedef unsigned int uint32;
typedef __attribute__((ext_vector_type(8))) short bf16x8;   // 8 bf16 = 4 VGPRs
typedef __attribute__((ext_vector_type(4))) float f32x4;

__device__ __forceinline__ void async16(void* lds, const void* g) {
  __builtin_amdgcn_global_load_lds((const __attribute__((address_space(1))) void*)g,
                                   (__attribute__((address_space(3))) void*)lds,
                                   16, 0, 0);
}
__device__ __forceinline__ ushort_t f2bf(float f) {
  uint32 u = __float_as_uint(f);
  u += 0x7FFFu + ((u >> 16) & 1u);   // round-to-nearest-even
  return (ushort_t)(u >> 16);
}
__device__ __forceinline__ float bf2f(ushort_t b) {
  return __uint_as_float(((uint32)b) << 16);
}
// value from lane^1 via DPP quad_perm [1,0,3,2] (VALU, no LDS)
__device__ __forceinline__ float dpp_xor1(float v) {
  return __int_as_float(__builtin_amdgcn_update_dpp(
      0, __float_as_int(v), 0xB1, 0xf, 0xf, true));
}
#define DPP_MAX(t, ctrl) \
  t = fmaxf(t, __int_as_float(__builtin_amdgcn_update_dpp( \
      0, __float_as_int(t), (ctrl), 0xf, 0xf, true)))
#define DPP_ADD(t, ctrl) \
  t += __int_as_float(__builtin_amdgcn_update_dpp( \
      0, __float_as_int(t), (ctrl), 0xf, 0xf, true))
__device__ __forceinline__ float rowmax16(float t) {
  DPP_MAX(t, 0xB1);   // xor 1
  DPP_MAX(t, 0x4E);   // xor 2
  t = fmaxf(t, __int_as_float(__builtin_amdgcn_ds_swizzle(
      __float_as_int(t), 0x101F)));                  // xor 4
  DPP_MAX(t, 0x128);  // row_ror:8 -> xor 8 (halves uniform after xor1/2/4)
  return t;
}
__device__ __forceinline__ float rowsum16(float t) {
  DPP_ADD(t, 0xB1);
  DPP_ADD(t, 0x4E);
  t += __int_as_float(__builtin_amdgcn_ds_swizzle(__float_as_int(t), 0x101F));
  DPP_ADD(t, 0x128);
  return t;
}

// ---------------------------------------------------------------------------
// cast x (fp32) -> bf16, 8 elements/thread
__global__ __launch_bounds__(256) void cast_x_kernel(const float* __restrict__ x,
                                                     ushort_t* __restrict__ Xb) {
  size_t i = ((size_t)blockIdx.x * 256 + threadIdx.x) * 8;
  float4 a = *(const float4*)(x + i);
  float4 b = *(const float4*)(x + i + 4);
  uint4 o;
  o.x = (uint32)f2bf(a.x) | ((uint32)f2bf(a.y) << 16);
  o.y = (uint32)f2bf(a.z) | ((uint32)f2bf(a.w) << 16);
  o.z = (uint32)f2bf(b.x) | ((uint32)f2bf(b.y) << 16);
  o.w = (uint32)f2bf(b.z) | ((uint32)f2bf(b.w) << 16);
  *(uint4*)(Xb + i) = o;
}

// ---------------------------------------------------------------------------
// W[k][n] fp32 -> Wt[n][k] bf16 (64x64 tiles), dword stores
__global__ __launch_bounds__(256) void transpose_w_kernel(
    const float* __restrict__ w0, const float* __restrict__ w1,
    const float* __restrict__ w2, const float* __restrict__ w3,
    ushort_t* __restrict__ outBase) {
  const float* W = (blockIdx.z == 0) ? w0 : (blockIdx.z == 1) ? w1
                 : (blockIdx.z == 2) ? w2 : w3;
  ushort_t* Wt = outBase + (size_t)blockIdx.z * 4194304;  // 2048*2048
  __shared__ float L[64][65];
  int t = threadIdx.x, tc = t & 63, tr = t >> 6;
  int k0 = blockIdx.x * 64, n0 = blockIdx.y * 64;
  for (int i = 0; i < 16; ++i) {
    int r = i * 4 + tr;
    L[r][tc] = W[(size_t)(k0 + r) * 2048 + n0 + tc];
  }
  __syncthreads();
  int tr8 = t >> 5, tc2 = t & 31;
  for (int i = 0; i < 8; ++i) {
    int r = i * 8 + tr8;
    uint32 pk = (uint32)f2bf(L[2 * tc2][r]) | ((uint32)f2bf(L[2 * tc2 + 1][r]) << 16);
    *(uint32*)(Wt + (size_t)(n0 + r) * 2048 + k0 + 2 * tc2) = pk;
  }
}

// ---------------------------------------------------------------------------
// adapter projections: ak/av[l][n] = sum_k adapter[l][k] * W[k][n]  (fp32)
// (R8 version: 256 blocks, atomic accumulate.)
__global__ __launch_bounds__(256) void adapter_kv_kernel(
    const float* __restrict__ adapter, const float* __restrict__ wk,
    const float* __restrict__ wv, float* __restrict__ ak, float* __restrict__ av) {
  const float* W = blockIdx.z ? wv : wk;
  float* out = blockIdx.z ? av : ak;
  __shared__ float As[10][128];
  int t = threadIdx.x;
  int k0 = blockIdx.y * 128;
  for (int i = t; i < 1280; i += 256)
    As[i >> 7][i & 127] = adapter[(size_t)(i >> 7) * 2048 + k0 + (i & 127)];
  __syncthreads();
  int n = blockIdx.x * 256 + t;
  float acc[10];
#pragma unroll
  for (int l = 0; l < 10; ++l) acc[l] = 0.f;
  for (int kk = 0; kk < 128; ++kk) {
    float wv_ = W[(size_t)(k0 + kk) * 2048 + n];
#pragma unroll
    for (int l = 0; l < 10; ++l) acc[l] += As[l][kk] * wv_;
  }
#pragma unroll
  for (int l = 0; l < 10; ++l) atomicAdd(&out[l * 2048 + n], acc[l]);
}

// ---------------------------------------------------------------------------
// pack ak/av (fp32) into MFMA-fragment-friendly bf16 buffers:
// akb[h][l(16)][d(128)] (l>=10 zero), avb[h][d(128)][l(32)] (l>=10 zero)
__global__ __launch_bounds__(256) void adapter_pack_kernel(
    const float* __restrict__ ak, const float* __restrict__ av,
    ushort_t* __restrict__ akb, ushort_t* __restrict__ avb) {
  int t = blockIdx.x * 256 + threadIdx.x;   // 65536 threads
  if (t < 32768) {
    int h = t >> 11, l = (t >> 7) & 15, d = t & 127;
    akb[t] = (l < 10) ? f2bf(ak[l * 2048 + h * 128 + d]) : (ushort_t)0;
  }
  int h = t >> 12, d = (t >> 5) & 127, l = t & 31;
  avb[t] = (l < 10) ? f2bf(av[l * 2048 + h * 128 + d]) : (ushort_t)0;
}

#define QK_BARX() asm volatile("s_barrier" ::: "memory")
#define QK_LGKM0() asm volatile("s_waitcnt lgkmcnt(0)" ::: "memory")

// ---------------------------------------------------------------------------
// QKV GEMM, 256x256 tile, 4-phase/K-tile (m201 port). C[4096,6144] =
// Xb[4096,2048] x WtQKV[6144,2048]^T. Grid 384 (16M x 24N), 512 thr.
// LDS 128KB: A [buf][kh][256r][64B] at 0 (64KB), B same at 65536.
// Phases: p0(mlo,k0) p1(mhi,k0) p2(mhi,k1) p3(mlo,k1); stages: p0 A-k1(t+1),
// p1 B-k1(t+1) [other buffer, safe], p2 A-k0(t+2), p3 B-k0(t+2) [same buffer,
// regions last read at p1]. vmcnt(4) at tile end (leaves p2,p3 stages in
// flight); vmcnt(0) at t==nt-2. Chunk swizzle c^(row&3) (4 chunks per K-half)
// applied on the pre-swizzled GLOBAL source; reads use quad^(row&3).
// ---------------------------------------------------------------------------
__global__ __launch_bounds__(512, 2) void gemm_qkv256_kernel(
    const ushort_t* __restrict__ A, const ushort_t* __restrict__ Bt,
    ushort_t* __restrict__ outQ, ushort_t* __restrict__ outK,
    ushort_t* __restrict__ Vt,
    const float* __restrict__ fc, const float* __restrict__ fs) {
  __shared__ char lds[131072];
  const int tid = (int)threadIdx.x;
  const int w = tid >> 6, lane = tid & 63, quad = lane >> 4, l15 = lane & 15;
  const int wr = w >> 2, wc = w & 3;
  const int nt = 32;

  // bijective XCD swizzle: 384 = 8 x 48; each XCD: 3 N-panels x 16 M-tiles.
  const int wg = ((int)blockIdx.x & 7) * 48 + ((int)blockIdx.x >> 3);
  const size_t bm0 = (size_t)(wg & 15) * 256;
  const size_t bn0 = (size_t)(wg >> 4) * 256;

// stage one (op, K-half) of tile T: 2 x async16 per thread (256 rows).
#define SEGH(OB, G, GROW, T, KH)                                               \
  do { if ((T) < nt) {                                                         \
    int c_ = lane & 3;                                                         \
    _Pragma("unroll") for (int L_ = 0; L_ < 2; ++L_) {                         \
      int r_ = L_ * 128 + w * 16 + (lane >> 2);                                \
      async16(lds + (OB) + (((T) & 1) * 32768) + (KH) * 16384 + L_ * 8192 + w * 1024, \
              (G) + ((GROW) + (size_t)r_) * 2048 +                             \
                  (size_t)((T) * 64 + (KH) * 32 + ((c_ ^ (r_ & 3)) * 8)));     \
    } } } while (0)
// frag read: row RA, k-half KS, buffer byte-offset BUF, op base OB
#define FRAG(OB, BUF, KS, RA) \
  (*(const bf16x8*)(lds + (OB) + (BUF) + (KS) * 16384 + (RA) * 64 + \
                    ((quad ^ ((RA) & 3)) * 16)))

  f32x4 acc[8][4];
  f32x4 z4 = {0.f, 0.f, 0.f, 0.f};
#pragma unroll
  for (int i = 0; i < 8; ++i)
#pragma unroll
    for (int j = 0; j < 4; ++j) acc[i][j] = z4;

  // prologue: k0(0), k1(0), k0(1) = 12 loads; wait to 4 (k0(1) in flight).
  SEGH(0, A, bm0, 0, 0); SEGH(65536, Bt, bn0, 0, 0);
  SEGH(0, A, bm0, 0, 1); SEGH(65536, Bt, bn0, 0, 1);
  SEGH(0, A, bm0, 1, 0); SEGH(65536, Bt, bn0, 1, 0);
  asm volatile("s_waitcnt vmcnt(4)" ::: "memory");
  QK_BARX();

  for (int t = 0; t < nt; ++t) {
    const int buf = (t & 1) * 32768;
    bf16x8 af[4], bfv[4];

    // ---- p0: (m-lo, k0) ----
#pragma unroll
    for (int j = 0; j < 4; ++j) bfv[j] = FRAG(65536, buf, 0, wc * 64 + j * 16 + l15);
#pragma unroll
    for (int i = 0; i < 4; ++i) af[i] = FRAG(0, buf, 0, wr * 128 + i * 16 + l15);
    SEGH(0, A, bm0, t + 1, 1);
    QK_BARX();
    QK_LGKM0();
    __builtin_amdgcn_s_setprio(1);
#pragma unroll
    for (int i = 0; i < 4; ++i)
#pragma unroll
      for (int j = 0; j < 4; ++j)
        acc[i][j] = __builtin_amdgcn_mfma_f32_16x16x32_bf16(af[i], bfv[j], acc[i][j], 0, 0, 0);
    __builtin_amdgcn_s_setprio(0);
    QK_BARX();

    // ---- p1: (m-hi, k0), B-k0 held ----
#pragma unroll
    for (int i = 0; i < 4; ++i) af[i] = FRAG(0, buf, 0, wr * 128 + (4 + i) * 16 + l15);
    SEGH(65536, Bt, bn0, t + 1, 1);
    QK_BARX();
    QK_LGKM0();
    __builtin_amdgcn_s_setprio(1);
#pragma unroll
    for (int i = 0; i < 4; ++i)
#pragma unroll
      for (int j = 0; j < 4; ++j)
        acc[4 + i][j] = __builtin_amdgcn_mfma_f32_16x16x32_bf16(af[i], bfv[j], acc[4 + i][j], 0, 0, 0);
    __builtin_amdgcn_s_setprio(0);
    QK_BARX();

    // ---- p2: (m-hi, k1) ----
#pragma unroll
    for (int j = 0; j < 4; ++j) bfv[j] = FRAG(65536, buf, 1, wc * 64 + j * 16 + l15);
#pragma unroll
    for (int i = 0; i < 4; ++i) af[i] = FRAG(0, buf, 1, wr * 128 + (4 + i) * 16 + l15);
    SEGH(0, A, bm0, t + 2, 0);
    QK_BARX();
    QK_LGKM0();
    __builtin_amdgcn_s_setprio(1);
#pragma unroll
    for (int i = 0; i < 4; ++i)
#pragma unroll
      for (int j = 0; j < 4; ++j)
        acc[4 + i][j] = __builtin_amdgcn_mfma_f32_16x16x32_bf16(af[i], bfv[j], acc[4 + i][j], 0, 0, 0);
    __builtin_amdgcn_s_setprio(0);
    QK_BARX();

    // ---- p3: (m-lo, k1), B-k1 held ----
#pragma unroll
    for (int i = 0; i < 4; ++i) af[i] = FRAG(0, buf, 1, wr * 128 + i * 16 + l15);
    SEGH(65536, Bt, bn0, t + 2, 0);
    QK_BARX();
    QK_LGKM0();
    __builtin_amdgcn_s_setprio(1);
#pragma unroll
    for (int i = 0; i < 4; ++i)
#pragma unroll
      for (int j = 0; j < 4; ++j)
        acc[i][j] = __builtin_amdgcn_mfma_f32_16x16x32_bf16(af[i], bfv[j], acc[i][j], 0, 0, 0);
    __builtin_amdgcn_s_setprio(0);
    if (t == nt - 2) asm volatile("s_waitcnt vmcnt(0)" ::: "memory");
    else             asm volatile("s_waitcnt vmcnt(4)" ::: "memory");
    QK_BARX();
  }
#undef SEGH
#undef FRAG

  // ---------------- epilogue ----------------
  const int seg = (int)(bn0 >> 11);   // 0=Q, 1=K, 2=V
  if (seg < 2) {
    ushort_t* ob = seg ? outK : outQ;
#pragma unroll
    for (int i = 0; i < 8; ++i)
#pragma unroll
      for (int r = 0; r < 4; ++r) {
        size_t m = bm0 + wr * 128 + i * 16 + quad * 4 + r;
        int s = (int)(m & 2047);
#pragma unroll
        for (int j = 0; j < 4; ++j) {
          size_t n = (bn0 + wc * 64 + j * 16 + l15) & 2047;
          float v = acc[i][j][r];
          float v2 = dpp_xor1(v);             // RoPE pair partner (col n^1)
          int fi = ((int)n & 127) >> 1;
          float cosv = fc[s * 64 + fi];
          float sinv = fs[s * 64 + fi];
          v = (lane & 1) ? (v2 * sinv + v * cosv) : (v * cosv - v2 * sinv);
          ob[m * 2048 + n] = f2bf(v);
        }
      }
  } else {
    // V segment: per-wave 64(n) x 128(m) transpose as two proven 64x64
    // passes through a private 16KB LDS patch (after the final barrier).
    char* T = lds + w * 16384;
    const int b = (int)(bm0 >> 11);
    const int n2 = (int)(bn0 & 2047) + wc * 64;
#pragma unroll
    for (int mh = 0; mh < 2; ++mh) {
#pragma unroll
      for (int i = 0; i < 4; ++i)
#pragma unroll
        for (int j = 0; j < 4; ++j) {
          int nn = j * 16 + l15;
          int md0 = i * 8 + quad * 2;
          const f32x4 av4 = acc[mh * 4 + i][j];
          uint32 p01 = (uint32)f2bf(av4[0]) | ((uint32)f2bf(av4[1]) << 16);
          uint32 p23 = (uint32)f2bf(av4[2]) | ((uint32)f2bf(av4[3]) << 16);
          *(uint32*)(T + nn * 128 + ((md0 ^ (nn & 31)) * 4)) = p01;
          *(uint32*)(T + nn * 128 + (((md0 + 1) ^ (nn & 31)) * 4)) = p23;
        }
      const int s0 = (int)(bm0 & 2047) + wr * 128 + mh * 64;
#pragma unroll
      for (int it = 0; it < 32; ++it) {
        int row = it * 2 + (lane >> 5);
        int pp = lane & 31;
        uint32 dv = *(const uint32*)(T + row * 128 + pp * 4);
        int md = pp ^ (row & 31);
        int nloc = n2 + row;
        size_t bh = (size_t)b * 16 + (nloc >> 7);
        *(uint32*)(Vt + (bh * 128 + (size_t)(nloc & 127)) * 2048 + s0 + 2 * md) = dv;
      }
    }
  }
}

// ---------------------------------------------------------------------------
// R8's proven pipelined 128x256 K-loop (A and B in LDS) for the wo GEMM.
__device__ __forceinline__ void kloop_128x256(
    char* lds, const ushort_t* __restrict__ A, const ushort_t* __restrict__ Bt,
    size_t bm0, size_t bn0, f32x4 (&acc)[4][4]) {
  const int tid = (int)threadIdx.x;
  const int w = tid >> 6, lane = tid & 63, quad = lane >> 4, l15 = lane & 15;
  const int wr = (w >> 2) * 64, wc = (w & 3) * 64;
  const int nt = 32;
  char* const pA0 = lds;
  char* const pA1 = lds + 16384;
  char* const pB0 = lds + 32768;
  char* const pB1 = lds + 65536;

#define PAT(T) (((T) & 1) ? pA1 : pA0)
#define PBT(T) (((T) & 1) ? pB1 : pB0)
#define SEGL(OP, LDSB, GROW, T)                                                \
  do {                                                                         \
    int rr_ = w * 8 + (lane >> 3);                                             \
    int cl_ = (lane & 7) ^ (rr_ & 7);                                          \
    async16((LDSB) + w * 1024,                                                 \
            (OP) + ((GROW) + (size_t)rr_) * 2048 + (size_t)((T) * 64 + cl_ * 8)); \
  } while (0)
#define ST_A(T)                                                                \
  do { if ((T) < nt) { SEGL(A, PAT(T), bm0, (T));                              \
                       SEGL(A, PAT(T) + 8192, bm0 + 64, (T)); } } while (0)
#define ST_B0(T)                                                               \
  do { if ((T) < nt) SEGL(Bt, PBT(T), bn0, (T)); } while (0)
#define ST_B123(T)                                                             \
  do { if ((T) < nt) { SEGL(Bt, PBT(T) + 8192,  bn0 + 64,  (T));               \
                       SEGL(Bt, PBT(T) + 16384, bn0 + 128, (T));               \
                       SEGL(Bt, PBT(T) + 24576, bn0 + 192, (T)); } } while (0)

  ST_A(0); ST_B0(0); ST_B123(0); ST_B123(1);
  asm volatile("s_waitcnt vmcnt(3)" ::: "memory");
  QK_BARX();

#pragma unroll 2
  for (int t = 0; t < nt; ++t) {
    const char* pA = PAT(t);
    const char* pB = PBT(t);
    bf16x8 bfv[4][2];
#pragma unroll
    for (int j = 0; j < 4; ++j) {
      int brow = wc + j * 16 + l15;
#pragma unroll
      for (int ks = 0; ks < 2; ++ks)
        bfv[j][ks] = *(const bf16x8*)(pB + brow * 128 +
                                      (((ks * 4 + quad) ^ (brow & 7)) * 16));
    }
#pragma unroll
    for (int ph = 0; ph < 2; ++ph) {
      bf16x8 af[2][2];
#pragma unroll
      for (int ii = 0; ii < 2; ++ii) {
        int arow = wr + (ph * 2 + ii) * 16 + l15;
#pragma unroll
        for (int ks = 0; ks < 2; ++ks)
          af[ii][ks] = *(const bf16x8*)(pA + arow * 128 +
                                        (((ks * 4 + quad) ^ (arow & 7)) * 16));
      }
      if (ph == 0) { ST_A(t + 1); ST_B0(t + 1); }
      else         { ST_B123(t + 2); }
      QK_BARX();
      QK_LGKM0();
      __builtin_amdgcn_s_setprio(1);
#pragma unroll
      for (int ks = 0; ks < 2; ++ks)
#pragma unroll
        for (int ii = 0; ii < 2; ++ii)
#pragma unroll
          for (int j = 0; j < 4; ++j)
            acc[ph * 2 + ii][j] = __builtin_amdgcn_mfma_f32_16x16x32_bf16(
                af[ii][ks], bfv[j][ks], acc[ph * 2 + ii][j], 0, 0, 0);
      __builtin_amdgcn_s_setprio(0);
      if (ph == 1) {
        if (t == nt - 2) asm volatile("s_waitcnt vmcnt(0)" ::: "memory");
        else             asm volatile("s_waitcnt vmcnt(3)" ::: "memory");
      }
      QK_BARX();
    }
  }
#undef PAT
#undef PBT
#undef SEGL
#undef ST_A
#undef ST_B0
#undef ST_B123
}

// ---------------------------------------------------------------------------
// Output projection: out[4096,2048] fp32 = Ob x WtO^T. Grid 256 = 1 round.
__global__ __launch_bounds__(512, 2) void gemm_wo_kernel(
    const ushort_t* __restrict__ A, const ushort_t* __restrict__ Bt,
    float* __restrict__ out) {
  __shared__ char lds[98304];
  const int tid = (int)threadIdx.x;
  const int w = tid >> 6, lane = tid & 63, quad = lane >> 4, l15 = lane & 15;
  const int wr = (w >> 2) * 64, wc = (w & 3) * 64;

  const int wg = ((int)blockIdx.x & 7) * 32 + ((int)blockIdx.x >> 3);
  const size_t bm0 = (size_t)(wg & 31) * 128;
  const size_t bn0 = (size_t)(wg >> 5) * 256;

  f32x4 acc[4][4];
  f32x4 z4 = {0.f, 0.f, 0.f, 0.f};
#pragma unroll
  for (int i = 0; i < 4; ++i)
#pragma unroll
    for (int j = 0; j < 4; ++j) acc[i][j] = z4;

  kloop_128x256(lds, A, Bt, bm0, bn0, acc);

#pragma unroll
  for (int i = 0; i < 4; ++i)
#pragma unroll
    for (int r = 0; r < 4; ++r) {
      size_t m = bm0 + wr + i * 16 + quad * 4 + r;
#pragma unroll
      for (int j = 0; j < 4; ++j) {
        size_t n = bn0 + wc + j * 16 + l15;
        out[m * 2048 + n] = acc[i][j][r];
      }
    }
}

// ---------------------------------------------------------------------------
// Flash attention, causal, + fused adapter attention. (R8 structure.)
__global__ __launch_bounds__(256, 4) void flash_kernel(
    const ushort_t* __restrict__ Qb, const ushort_t* __restrict__ Kb,
    const ushort_t* __restrict__ Vt, const ushort_t* __restrict__ akb,
    const ushort_t* __restrict__ avb, const float* __restrict__ gate,
    ushort_t* __restrict__ Ob) {
  __shared__ char ldsK[16384];   // 64 tok x 256B, chunk swz ^(row&15)
  __shared__ char ldsV[16384];   // 128 d x 128B, chunk swz ^(dr&7)
  __shared__ char ldsP[8192];    // loop: P 64q x 128B swz; epilogue: pa[64][40]
  const int tid = threadIdx.x;
  const int w = tid >> 6, lane = tid & 63, quad = lane >> 4, l15 = lane & 15;
  const int idx = blockIdx.x;
  const int pg = idx >> 8, c = idx & 255;
  const int u = c >> 3, vv = c & 7;
  const int uu = (pg & 2) ? ((u + 16) & 31) : u;
  const int qt2 = (pg & 1) ? (31 - uu) : uu;     // 64-row q-tile index [0,32)
  const int hb = (pg << 3) | vv;                 // [0,32)
  const int h = hb >> 1, b = hb & 1;
  const float scale = 0.08838834764831845f;      // 1/sqrt(128)

  bf16x8 ones;
#pragma unroll
  for (int j = 0; j < 8; ++j) ones[j] = (short)0x3F80;

  bf16x8 qf[4];
  {
    size_t qrow = (size_t)qt2 * 64 + w * 16 + l15;
    const ushort_t* base = Qb + ((size_t)b * 2048 + qrow) * 2048 + h * 128 + quad * 8;
#pragma unroll
    for (int ds = 0; ds < 4; ++ds) qf[ds] = *(const bf16x8*)(base + ds * 32);
  }

  f32x4 zero4 = {0.f, 0.f, 0.f, 0.f};
  f32x4 oacc[8];
  f32x4 osum = zero4;
  float mrow[4];
#pragma unroll
  for (int n8 = 0; n8 < 8; ++n8) oacc[n8] = zero4;
#pragma unroll
  for (int r = 0; r < 4; ++r) mrow[r] = -1e30f;

  for (int kt = 0; kt <= qt2; ++kt) {
#pragma unroll
    for (int ii = 0; ii < 4; ++ii) {
      int r0 = w * 16 + ii * 4;
      int row = r0 + (lane >> 4);
      int cl = (lane & 15) ^ (row & 15);
      async16(ldsK + r0 * 256,
              Kb + ((size_t)b * 2048 + kt * 64 + row) * 2048 + h * 128 + cl * 8);
    }
#pragma unroll
    for (int ii = 0; ii < 4; ++ii) {
      int d0 = w * 32 + ii * 8;
      int dr = d0 + (lane >> 3);
      int cl = (lane & 7) ^ (dr & 7);
      async16(ldsV + d0 * 128,
              Vt + ((size_t)(b * 16 + h) * 128 + dr) * 2048 + kt * 64 + cl * 8);
    }
    __syncthreads();

    f32x4 sacc[4];
#pragma unroll
    for (int nt = 0; nt < 4; ++nt) sacc[nt] = zero4;
#pragma unroll
    for (int ds = 0; ds < 4; ++ds) {
      bf16x8 kf[4];
      int ch = ds * 4 + quad;
#pragma unroll
      for (int nt = 0; nt < 4; ++nt) {
        int row = nt * 16 + l15;
        kf[nt] = *(const bf16x8*)(ldsK + row * 256 + ((ch ^ (row & 15)) * 16));
      }
#pragma unroll
      for (int nt = 0; nt < 4; ++nt)
        sacc[nt] = __builtin_amdgcn_mfma_f32_16x16x32_bf16(qf[ds], kf[nt], sacc[nt], 0, 0, 0);
    }

    const bool domask = (kt == qt2);
    float tmax[4] = {-1e30f, -1e30f, -1e30f, -1e30f};
    const int qbr = qt2 * 64 + w * 16 + quad * 4;
#pragma unroll
    for (int nt = 0; nt < 4; ++nt) {
      int kg = kt * 64 + nt * 16 + l15;
#pragma unroll
      for (int r = 0; r < 4; ++r) {
        float s = sacc[nt][r] * scale;
        if (domask && kg > qbr + r) s = -1e30f;
        sacc[nt][r] = s;
        tmax[r] = fmaxf(tmax[r], s);
      }
    }
    float need = 0.f;
#pragma unroll
    for (int r = 0; r < 4; ++r) {
      tmax[r] = rowmax16(tmax[r]);
      need = fmaxf(need, tmax[r] - mrow[r]);
    }
    if (__any(need > 8.0f)) {
      float alpha[4];
#pragma unroll
      for (int r = 0; r < 4; ++r) {
        float mnew = fmaxf(mrow[r], tmax[r]);
        alpha[r] = __expf(mrow[r] - mnew);
        osum[r] *= alpha[r];
        mrow[r] = mnew;
      }
#pragma unroll
      for (int n8 = 0; n8 < 8; ++n8)
#pragma unroll
        for (int r = 0; r < 4; ++r) oacc[n8][r] *= alpha[r];
    }
    uint32 pk[4][4];
#pragma unroll
    for (int nt = 0; nt < 4; ++nt)
#pragma unroll
      for (int r = 0; r < 4; ++r) {
        float pv = __expf(sacc[nt][r] - mrow[r]);
        float pn = dpp_xor1(pv);
        uint32 d_;
        asm volatile("v_cvt_pk_bf16_f32 %0, %1, %2" : "=v"(d_) : "v"(pv), "v"(pn));
        pk[nt][r] = d_;
      }
    if (!(lane & 1)) {
#pragma unroll
      for (int nt = 0; nt < 4; ++nt)
#pragma unroll
        for (int r = 0; r < 4; ++r) {
          int col = nt * 16 + l15;   // even
          int prow = w * 16 + quad * 4 + r;
          *(uint32*)(ldsP + prow * 128 + (((col >> 3) ^ (prow & 7)) * 16) + (col & 7) * 2) = pk[nt][r];
        }
    }

#pragma unroll
    for (int ks = 0; ks < 2; ++ks) {
      int ch = ks * 4 + quad;
      int prow = w * 16 + l15;
      bf16x8 pf = *(const bf16x8*)(ldsP + prow * 128 + ((ch ^ (prow & 7)) * 16));
      osum = __builtin_amdgcn_mfma_f32_16x16x32_bf16(pf, ones, osum, 0, 0, 0);
#pragma unroll
      for (int n8 = 0; n8 < 8; ++n8) {
        int dr = n8 * 16 + l15;
        bf16x8 vf = *(const bf16x8*)(ldsV + dr * 128 + ((ch ^ (dr & 7)) * 16));
        oacc[n8] = __builtin_amdgcn_mfma_f32_16x16x32_bf16(pf, vf, oacc[n8], 0, 0, 0);
      }
    }
    __syncthreads();
  }

  // ---------------- fused adapter epilogue ----------------
  const float g = gate[h];
  {
    int row = w * 16 + (lane >> 2);
    *(uint2*)(ldsP + row * 80 + 32 + (lane & 3) * 8) = make_uint2(0, 0);
  }
  f32x4 sa = zero4;
#pragma unroll
  for (int ds = 0; ds < 4; ++ds) {
    bf16x8 kfa = *(const bf16x8*)(akb + ((size_t)h * 16 + l15) * 128 + ds * 32 + quad * 8);
    sa = __builtin_amdgcn_mfma_f32_16x16x32_bf16(qf[ds], kfa, sa, 0, 0, 0);
  }
#pragma unroll
  for (int r = 0; r < 4; ++r) {
    float s = sa[r] * scale;
    if (l15 >= 10) s = -1e30f;
    float mx = rowmax16(s);
    float e = __expf(s - mx);
    float sum = rowsum16(e);
    float pv = g * e / sum;
    int row = w * 16 + quad * 4 + r;
    *(ushort_t*)(ldsP + row * 80 + l15 * 2) = f2bf(pv);
  }
  bf16x8 paf = *(const bf16x8*)(ldsP + (w * 16 + l15) * 80 + quad * 16);

  float rl[4];
#pragma unroll
  for (int r = 0; r < 4; ++r) rl[r] = 1.f / osum[r];
#pragma unroll
  for (int n8 = 0; n8 < 8; ++n8)
#pragma unroll
    for (int r = 0; r < 4; ++r) oacc[n8][r] *= rl[r];
#pragma unroll
  for (int n8 = 0; n8 < 8; ++n8) {
    bf16x8 avf = *(const bf16x8*)(avb + ((size_t)h * 128 + n8 * 16 + l15) * 32 + quad * 8);
    oacc[n8] = __builtin_amdgcn_mfma_f32_16x16x32_bf16(paf, avf, oacc[n8], 0, 0, 0);
  }
  size_t qb0 = (size_t)qt2 * 64 + w * 16 + quad * 4;
#pragma unroll
  for (int n8 = 0; n8 < 8; ++n8) {
    size_t col = (size_t)h * 128 + n8 * 16 + l15;
#pragma unroll
    for (int r = 0; r < 4; ++r)
      Ob[((size_t)b * 2048 + qb0 + r) * 2048 + col] = f2bf(oacc[n8][r]);
  }
}

// ---------------------------------------------------------------------------
extern "C" void kernel_launch(void* const* d_in, const int* in_sizes, int n_in,
                              void* d_out, int out_size, void* d_ws, size_t ws_size,
                              hipStream_t stream) {
  (void)in_sizes; (void)n_in; (void)out_size; (void)ws_size;
  const float* x       = (const float*)d_in[0];
  const float* wq      = (const float*)d_in[1];
  const float* wk      = (const float*)d_in[2];
  const float* wv      = (const float*)d_in[3];
  const float* wo      = (const float*)d_in[4];
  const float* adapter = (const float*)d_in[5];
  const float* gate    = (const float*)d_in[6];
  const float* fc      = (const float*)d_in[7];
  const float* fs      = (const float*)d_in[8];

  char* ws = (char*)d_ws;
  ushort_t* Xb   = (ushort_t*)(ws + 0);           // 16 MB (reused as Ob)
  ushort_t* WtQ  = (ushort_t*)(ws + 16777216);    // 8 MB x4 contiguous
  ushort_t* WtO  = (ushort_t*)(ws + 41943040);
  ushort_t* Qb   = (ushort_t*)(ws + 50331648);    // 16 MB
  ushort_t* Kb   = (ushort_t*)(ws + 67108864);    // 16 MB
  ushort_t* Vt   = (ushort_t*)(ws + 83886080);    // 16 MB
  float*    ak   = (float*)   (ws + 100663296);   // 80 KB
  float*    av   = (float*)   (ws + 100745216);   // 80 KB
  ushort_t* akb  = (ushort_t*)(ws + 100827136);   // 64 KB
  ushort_t* avb  = (ushort_t*)(ws + 100892672);   // 128 KB
  ushort_t* Ob   = Xb;

  cast_x_kernel<<<4096, 256, 0, stream>>>(x, Xb);
  transpose_w_kernel<<<dim3(32, 32, 4), 256, 0, stream>>>(wq, wk, wv, wo, WtQ);
  hipMemsetAsync(ak, 0, 163840, stream);
  adapter_kv_kernel<<<dim3(8, 16, 2), 256, 0, stream>>>(adapter, wk, wv, ak, av);
  adapter_pack_kernel<<<256, 256, 0, stream>>>(ak, av, akb, avb);
  gemm_qkv256_kernel<<<dim3(384), 512, 0, stream>>>(Xb, WtQ, Qb, Kb, Vt, fc, fs);
  flash_kernel<<<dim3(1024), 256, 0, stream>>>(Qb, Kb, Vt, akb, avb, gate, Ob);
  gemm_wo_kernel<<<dim3(256), 512, 0, stream>>>(Ob, WtO, (float*)d_out);
}

// Round 6
// 441.016 us; speedup vs baseline: 1.8475x; 1.0313x over previous
//
#include <hip/hip_runtime.h>

// ---------------------------------------------------------------------------
// Attention_16698832847178: B=2,S=2048,D=2048,H=16,HD=128,L=10
// R11: fix R10's LDS layout (64B rows -> 4-way bank conflicts, 9.57M counted).
// 256x256 4-phase kept, but rows stored full-BK (128B) with the proven
// chunk^(row&7) 8-chunk swizzle (conflict-free, 131K in R7/R8). Staging
// simplified: all 8 slots of tile t+1 staged during tile t into the OPPOSITE
// buffer (2 slots/phase; A-mhi last), counted vmcnt(2) at p0-end and p3-end.
// flash/wo/pre-kernels unchanged (R8 state).
// ---------------------------------------------------------------------------

typedef unsigned short ushort_t;
typedef unsigned int uint32;
typedef __attribute__((ext_vector_type(8))) short bf16x8;   // 8 bf16 = 4 VGPRs
typedef __attribute__((ext_vector_type(4))) float f32x4;

__device__ __forceinline__ void async16(void* lds, const void* g) {
  __builtin_amdgcn_global_load_lds((const __attribute__((address_space(1))) void*)g,
                                   (__attribute__((address_space(3))) void*)lds,
                                   16, 0, 0);
}
__device__ __forceinline__ ushort_t f2bf(float f) {
  uint32 u = __float_as_uint(f);
  u += 0x7FFFu + ((u >> 16) & 1u);   // round-to-nearest-even
  return (ushort_t)(u >> 16);
}
__device__ __forceinline__ float bf2f(ushort_t b) {
  return __uint_as_float(((uint32)b) << 16);
}
// value from lane^1 via DPP quad_perm [1,0,3,2] (VALU, no LDS)
__device__ __forceinline__ float dpp_xor1(float v) {
  return __int_as_float(__builtin_amdgcn_update_dpp(
      0, __float_as_int(v), 0xB1, 0xf, 0xf, true));
}
#define DPP_MAX(t, ctrl) \
  t = fmaxf(t, __int_as_float(__builtin_amdgcn_update_dpp( \
      0, __float_as_int(t), (ctrl), 0xf, 0xf, true)))
#define DPP_ADD(t, ctrl) \
  t += __int_as_float(__builtin_amdgcn_update_dpp( \
      0, __float_as_int(t), (ctrl), 0xf, 0xf, true))
__device__ __forceinline__ float rowmax16(float t) {
  DPP_MAX(t, 0xB1);   // xor 1
  DPP_MAX(t, 0x4E);   // xor 2
  t = fmaxf(t, __int_as_float(__builtin_amdgcn_ds_swizzle(
      __float_as_int(t), 0x101F)));                  // xor 4
  DPP_MAX(t, 0x128);  // row_ror:8 -> xor 8 (halves uniform after xor1/2/4)
  return t;
}
__device__ __forceinline__ float rowsum16(float t) {
  DPP_ADD(t, 0xB1);
  DPP_ADD(t, 0x4E);
  t += __int_as_float(__builtin_amdgcn_ds_swizzle(__float_as_int(t), 0x101F));
  DPP_ADD(t, 0x128);
  return t;
}

// ---------------------------------------------------------------------------
// cast x (fp32) -> bf16, 8 elements/thread
__global__ __launch_bounds__(256) void cast_x_kernel(const float* __restrict__ x,
                                                     ushort_t* __restrict__ Xb) {
  size_t i = ((size_t)blockIdx.x * 256 + threadIdx.x) * 8;
  float4 a = *(const float4*)(x + i);
  float4 b = *(const float4*)(x + i + 4);
  uint4 o;
  o.x = (uint32)f2bf(a.x) | ((uint32)f2bf(a.y) << 16);
  o.y = (uint32)f2bf(a.z) | ((uint32)f2bf(a.w) << 16);
  o.z = (uint32)f2bf(b.x) | ((uint32)f2bf(b.y) << 16);
  o.w = (uint32)f2bf(b.z) | ((uint32)f2bf(b.w) << 16);
  *(uint4*)(Xb + i) = o;
}

// ---------------------------------------------------------------------------
// W[k][n] fp32 -> Wt[n][k] bf16 (64x64 tiles), dword stores
__global__ __launch_bounds__(256) void transpose_w_kernel(
    const float* __restrict__ w0, const float* __restrict__ w1,
    const float* __restrict__ w2, const float* __restrict__ w3,
    ushort_t* __restrict__ outBase) {
  const float* W = (blockIdx.z == 0) ? w0 : (blockIdx.z == 1) ? w1
                 : (blockIdx.z == 2) ? w2 : w3;
  ushort_t* Wt = outBase + (size_t)blockIdx.z * 4194304;  // 2048*2048
  __shared__ float L[64][65];
  int t = threadIdx.x, tc = t & 63, tr = t >> 6;
  int k0 = blockIdx.x * 64, n0 = blockIdx.y * 64;
  for (int i = 0; i < 16; ++i) {
    int r = i * 4 + tr;
    L[r][tc] = W[(size_t)(k0 + r) * 2048 + n0 + tc];
  }
  __syncthreads();
  int tr8 = t >> 5, tc2 = t & 31;
  for (int i = 0; i < 8; ++i) {
    int r = i * 8 + tr8;
    uint32 pk = (uint32)f2bf(L[2 * tc2][r]) | ((uint32)f2bf(L[2 * tc2 + 1][r]) << 16);
    *(uint32*)(Wt + (size_t)(n0 + r) * 2048 + k0 + 2 * tc2) = pk;
  }
}

// ---------------------------------------------------------------------------
// adapter projections: ak/av[l][n] = sum_k adapter[l][k] * W[k][n]  (fp32)
__global__ __launch_bounds__(256) void adapter_kv_kernel(
    const float* __restrict__ adapter, const float* __restrict__ wk,
    const float* __restrict__ wv, float* __restrict__ ak, float* __restrict__ av) {
  const float* W = blockIdx.z ? wv : wk;
  float* out = blockIdx.z ? av : ak;
  __shared__ float As[10][128];
  int t = threadIdx.x;
  int k0 = blockIdx.y * 128;
  for (int i = t; i < 1280; i += 256)
    As[i >> 7][i & 127] = adapter[(size_t)(i >> 7) * 2048 + k0 + (i & 127)];
  __syncthreads();
  int n = blockIdx.x * 256 + t;
  float acc[10];
#pragma unroll
  for (int l = 0; l < 10; ++l) acc[l] = 0.f;
  for (int kk = 0; kk < 128; ++kk) {
    float wv_ = W[(size_t)(k0 + kk) * 2048 + n];
#pragma unroll
    for (int l = 0; l < 10; ++l) acc[l] += As[l][kk] * wv_;
  }
#pragma unroll
  for (int l = 0; l < 10; ++l) atomicAdd(&out[l * 2048 + n], acc[l]);
}

// ---------------------------------------------------------------------------
// pack ak/av (fp32) into MFMA-fragment-friendly bf16 buffers:
// akb[h][l(16)][d(128)] (l>=10 zero), avb[h][d(128)][l(32)] (l>=10 zero)
__global__ __launch_bounds__(256) void adapter_pack_kernel(
    const float* __restrict__ ak, const float* __restrict__ av,
    ushort_t* __restrict__ akb, ushort_t* __restrict__ avb) {
  int t = blockIdx.x * 256 + threadIdx.x;   // 65536 threads
  if (t < 32768) {
    int h = t >> 11, l = (t >> 7) & 15, d = t & 127;
    akb[t] = (l < 10) ? f2bf(ak[l * 2048 + h * 128 + d]) : (ushort_t)0;
  }
  int h = t >> 12, d = (t >> 5) & 127, l = t & 31;
  avb[t] = (l < 10) ? f2bf(av[l * 2048 + h * 128 + d]) : (ushort_t)0;
}

#define QK_BARX() asm volatile("s_barrier" ::: "memory")
#define QK_LGKM0() asm volatile("s_waitcnt lgkmcnt(0)" ::: "memory")

// ---------------------------------------------------------------------------
// QKV GEMM, 256x256 tile, 4-phase/K-tile. C[4096,6144] = Xb x WtQKV^T.
// Grid 384 (16M x 24N), 512 thr = 8 waves (2M x 4N), per-wave C 128x64
// (acc[8][4]). LDS 128KB: A dbuf [2][256r][128B] at 0, B dbuf at 65536.
// Rows full-BK (128B), chunk swizzle c^(row&7) pre-applied on the global
// source; frag reads use (ks*4+quad)^(row&7) -> conflict-free (R7-proven).
// Staging: all 8 slots (64 rows each) of tile t+1 during tile t into the
// OPPOSITE buffer: p0 B0,B1 | p1 B2,B3 | p2 A0,A2 (m-lo) | p3 A1,A3 (m-hi).
// Waits: vmcnt(2) end-of-p0 (retire cur A-mhi; vmcnt(0) on last tile),
// vmcnt(2) end-of-p3 (retire next B + A-mlo, keep next A-mhi in flight).
// ---------------------------------------------------------------------------
__global__ __launch_bounds__(512, 2) void gemm_qkv256_kernel(
    const ushort_t* __restrict__ A, const ushort_t* __restrict__ Bt,
    ushort_t* __restrict__ outQ, ushort_t* __restrict__ outK,
    ushort_t* __restrict__ Vt,
    const float* __restrict__ fc, const float* __restrict__ fs) {
  __shared__ char lds[131072];
  const int tid = (int)threadIdx.x;
  const int w = tid >> 6, lane = tid & 63, quad = lane >> 4, l15 = lane & 15;
  const int wr = w >> 2, wc = w & 3;
  const int nt = 32;

  // bijective XCD swizzle: 384 = 8 x 48; each XCD: 3 N-panels x 16 M-tiles.
  const int wg = ((int)blockIdx.x & 7) * 48 + ((int)blockIdx.x >> 3);
  const size_t bm0 = (size_t)(wg & 15) * 256;
  const size_t bn0 = (size_t)(wg >> 4) * 256;

// stage one 64-row slot S (8KB) of tile T: 1 async16/thread.
// OB: 0 for A, 65536 for B. Wave-uniform LDS dest; lane offset implicit.
#define STSL(OB, G, GROW, T, S)                                                \
  do { if ((T) < nt) {                                                         \
    int r_ = (S) * 64 + w * 8 + (lane >> 3);                                   \
    int cl_ = (lane & 7) ^ (r_ & 7);                                           \
    async16(lds + (OB) + (((T) & 1) * 32768) + (S) * 8192 + w * 1024,          \
            (G) + ((GROW) + (size_t)r_) * 2048 +                               \
                (size_t)((T) * 64 + cl_ * 8));                                 \
  } } while (0)
// frag read: op base OB, buffer byte-offset BUF, k-half KS, row RA
#define FRAG(OB, BUF, KS, RA) \
  (*(const bf16x8*)(lds + (OB) + (BUF) + (RA) * 128 + \
                    ((((KS) * 4 + quad) ^ ((RA) & 7)) * 16)))

  f32x4 acc[8][4];
  f32x4 z4 = {0.f, 0.f, 0.f, 0.f};
#pragma unroll
  for (int i = 0; i < 8; ++i)
#pragma unroll
    for (int j = 0; j < 4; ++j) acc[i][j] = z4;

  // prologue: tile0's 8 slots, A-mhi (A1,A3) last; wait to 2 outstanding.
  STSL(65536, Bt, bn0, 0, 0); STSL(65536, Bt, bn0, 0, 1);
  STSL(65536, Bt, bn0, 0, 2); STSL(65536, Bt, bn0, 0, 3);
  STSL(0, A, bm0, 0, 0); STSL(0, A, bm0, 0, 2);
  STSL(0, A, bm0, 0, 1); STSL(0, A, bm0, 0, 3);
  asm volatile("s_waitcnt vmcnt(2)" ::: "memory");
  QK_BARX();

  for (int t = 0; t < nt; ++t) {
    const int buf = (t & 1) * 32768;
    bf16x8 af[4], bfv[4];

    // ---- p0: (m-lo, k0) ----
#pragma unroll
    for (int j = 0; j < 4; ++j) bfv[j] = FRAG(65536, buf, 0, wc * 64 + j * 16 + l15);
#pragma unroll
    for (int i = 0; i < 4; ++i) af[i] = FRAG(0, buf, 0, wr * 128 + i * 16 + l15);
    STSL(65536, Bt, bn0, t + 1, 0); STSL(65536, Bt, bn0, t + 1, 1);
    QK_BARX();
    QK_LGKM0();
    __builtin_amdgcn_s_setprio(1);
#pragma unroll
    for (int i = 0; i < 4; ++i)
#pragma unroll
      for (int j = 0; j < 4; ++j)
        acc[i][j] = __builtin_amdgcn_mfma_f32_16x16x32_bf16(af[i], bfv[j], acc[i][j], 0, 0, 0);
    __builtin_amdgcn_s_setprio(0);
    if (t == nt - 1) asm volatile("s_waitcnt vmcnt(0)" ::: "memory");
    else             asm volatile("s_waitcnt vmcnt(2)" ::: "memory");
    QK_BARX();

    // ---- p1: (m-hi, k0), B-k0 held in regs ----
#pragma unroll
    for (int i = 0; i < 4; ++i) af[i] = FRAG(0, buf, 0, wr * 128 + (4 + i) * 16 + l15);
    STSL(65536, Bt, bn0, t + 1, 2); STSL(65536, Bt, bn0, t + 1, 3);
    QK_BARX();
    QK_LGKM0();
    __builtin_amdgcn_s_setprio(1);
#pragma unroll
    for (int i = 0; i < 4; ++i)
#pragma unroll
      for (int j = 0; j < 4; ++j)
        acc[4 + i][j] = __builtin_amdgcn_mfma_f32_16x16x32_bf16(af[i], bfv[j], acc[4 + i][j], 0, 0, 0);
    __builtin_amdgcn_s_setprio(0);
    QK_BARX();

    // ---- p2: (m-hi, k1) ----
#pragma unroll
    for (int j = 0; j < 4; ++j) bfv[j] = FRAG(65536, buf, 1, wc * 64 + j * 16 + l15);
#pragma unroll
    for (int i = 0; i < 4; ++i) af[i] = FRAG(0, buf, 1, wr * 128 + (4 + i) * 16 + l15);
    STSL(0, A, bm0, t + 1, 0); STSL(0, A, bm0, t + 1, 2);
    QK_BARX();
    QK_LGKM0();
    __builtin_amdgcn_s_setprio(1);
#pragma unroll
    for (int i = 0; i < 4; ++i)
#pragma unroll
      for (int j = 0; j < 4; ++j)
        acc[4 + i][j] = __builtin_amdgcn_mfma_f32_16x16x32_bf16(af[i], bfv[j], acc[4 + i][j], 0, 0, 0);
    __builtin_amdgcn_s_setprio(0);
    QK_BARX();

    // ---- p3: (m-lo, k1), B-k1 held ----
#pragma unroll
    for (int i = 0; i < 4; ++i) af[i] = FRAG(0, buf, 1, wr * 128 + i * 16 + l15);
    STSL(0, A, bm0, t + 1, 1); STSL(0, A, bm0, t + 1, 3);
    QK_BARX();
    QK_LGKM0();
    __builtin_amdgcn_s_setprio(1);
#pragma unroll
    for (int i = 0; i < 4; ++i)
#pragma unroll
      for (int j = 0; j < 4; ++j)
        acc[i][j] = __builtin_amdgcn_mfma_f32_16x16x32_bf16(af[i], bfv[j], acc[i][j], 0, 0, 0);
    __builtin_amdgcn_s_setprio(0);
    asm volatile("s_waitcnt vmcnt(2)" ::: "memory");
    QK_BARX();
  }
#undef STSL
#undef FRAG

  // ---------------- epilogue ----------------
  const int seg = (int)(bn0 >> 11);   // 0=Q, 1=K, 2=V
  if (seg < 2) {
    ushort_t* ob = seg ? outK : outQ;
#pragma unroll
    for (int i = 0; i < 8; ++i)
#pragma unroll
      for (int r = 0; r < 4; ++r) {
        size_t m = bm0 + wr * 128 + i * 16 + quad * 4 + r;
        int s = (int)(m & 2047);
#pragma unroll
        for (int j = 0; j < 4; ++j) {
          size_t n = (bn0 + wc * 64 + j * 16 + l15) & 2047;
          float v = acc[i][j][r];
          float v2 = dpp_xor1(v);             // RoPE pair partner (col n^1)
          int fi = ((int)n & 127) >> 1;
          float cosv = fc[s * 64 + fi];
          float sinv = fs[s * 64 + fi];
          v = (lane & 1) ? (v2 * sinv + v * cosv) : (v * cosv - v2 * sinv);
          ob[m * 2048 + n] = f2bf(v);
        }
      }
  } else {
    // V segment: per-wave 64(n) x 128(m) transpose as two proven 64x64
    // passes through a private 16KB LDS patch (after the final barrier).
    char* T = lds + w * 16384;
    const int b = (int)(bm0 >> 11);
    const int n2 = (int)(bn0 & 2047) + wc * 64;
#pragma unroll
    for (int mh = 0; mh < 2; ++mh) {
#pragma unroll
      for (int i = 0; i < 4; ++i)
#pragma unroll
        for (int j = 0; j < 4; ++j) {
          int nn = j * 16 + l15;
          int md0 = i * 8 + quad * 2;
          const f32x4 av4 = acc[mh * 4 + i][j];
          uint32 p01 = (uint32)f2bf(av4[0]) | ((uint32)f2bf(av4[1]) << 16);
          uint32 p23 = (uint32)f2bf(av4[2]) | ((uint32)f2bf(av4[3]) << 16);
          *(uint32*)(T + nn * 128 + ((md0 ^ (nn & 31)) * 4)) = p01;
          *(uint32*)(T + nn * 128 + (((md0 + 1) ^ (nn & 31)) * 4)) = p23;
        }
      const int s0 = (int)(bm0 & 2047) + wr * 128 + mh * 64;
#pragma unroll
      for (int it = 0; it < 32; ++it) {
        int row = it * 2 + (lane >> 5);
        int pp = lane & 31;
        uint32 dv = *(const uint32*)(T + row * 128 + pp * 4);
        int md = pp ^ (row & 31);
        int nloc = n2 + row;
        size_t bh = (size_t)b * 16 + (nloc >> 7);
        *(uint32*)(Vt + (bh * 128 + (size_t)(nloc & 127)) * 2048 + s0 + 2 * md) = dv;
      }
    }
  }
}

// ---------------------------------------------------------------------------
// R8's proven pipelined 128x256 K-loop (A and B in LDS) for the wo GEMM.
__device__ __forceinline__ void kloop_128x256(
    char* lds, const ushort_t* __restrict__ A, const ushort_t* __restrict__ Bt,
    size_t bm0, size_t bn0, f32x4 (&acc)[4][4]) {
  const int tid = (int)threadIdx.x;
  const int w = tid >> 6, lane = tid & 63, quad = lane >> 4, l15 = lane & 15;
  const int wr = (w >> 2) * 64, wc = (w & 3) * 64;
  const int nt = 32;
  char* const pA0 = lds;
  char* const pA1 = lds + 16384;
  char* const pB0 = lds + 32768;
  char* const pB1 = lds + 65536;

#define PAT(T) (((T) & 1) ? pA1 : pA0)
#define PBT(T) (((T) & 1) ? pB1 : pB0)
#define SEGL(OP, LDSB, GROW, T)                                                \
  do {                                                                         \
    int rr_ = w * 8 + (lane >> 3);                                             \
    int cl_ = (lane & 7) ^ (rr_ & 7);                                          \
    async16((LDSB) + w * 1024,                                                 \
            (OP) + ((GROW) + (size_t)rr_) * 2048 + (size_t)((T) * 64 + cl_ * 8)); \
  } while (0)
#define ST_A(T)                                                                \
  do { if ((T) < nt) { SEGL(A, PAT(T), bm0, (T));                              \
                       SEGL(A, PAT(T) + 8192, bm0 + 64, (T)); } } while (0)
#define ST_B0(T)                                                               \
  do { if ((T) < nt) SEGL(Bt, PBT(T), bn0, (T)); } while (0)
#define ST_B123(T)                                                             \
  do { if ((T) < nt) { SEGL(Bt, PBT(T) + 8192,  bn0 + 64,  (T));               \
                       SEGL(Bt, PBT(T) + 16384, bn0 + 128, (T));               \
                       SEGL(Bt, PBT(T) + 24576, bn0 + 192, (T)); } } while (0)

  ST_A(0); ST_B0(0); ST_B123(0); ST_B123(1);
  asm volatile("s_waitcnt vmcnt(3)" ::: "memory");
  QK_BARX();

#pragma unroll 2
  for (int t = 0; t < nt; ++t) {
    const char* pA = PAT(t);
    const char* pB = PBT(t);
    bf16x8 bfv[4][2];
#pragma unroll
    for (int j = 0; j < 4; ++j) {
      int brow = wc + j * 16 + l15;
#pragma unroll
      for (int ks = 0; ks < 2; ++ks)
        bfv[j][ks] = *(const bf16x8*)(pB + brow * 128 +
                                      (((ks * 4 + quad) ^ (brow & 7)) * 16));
    }
#pragma unroll
    for (int ph = 0; ph < 2; ++ph) {
      bf16x8 af[2][2];
#pragma unroll
      for (int ii = 0; ii < 2; ++ii) {
        int arow = wr + (ph * 2 + ii) * 16 + l15;
#pragma unroll
        for (int ks = 0; ks < 2; ++ks)
          af[ii][ks] = *(const bf16x8*)(pA + arow * 128 +
                                        (((ks * 4 + quad) ^ (arow & 7)) * 16));
      }
      if (ph == 0) { ST_A(t + 1); ST_B0(t + 1); }
      else         { ST_B123(t + 2); }
      QK_BARX();
      QK_LGKM0();
      __builtin_amdgcn_s_setprio(1);
#pragma unroll
      for (int ks = 0; ks < 2; ++ks)
#pragma unroll
        for (int ii = 0; ii < 2; ++ii)
#pragma unroll
          for (int j = 0; j < 4; ++j)
            acc[ph * 2 + ii][j] = __builtin_amdgcn_mfma_f32_16x16x32_bf16(
                af[ii][ks], bfv[j][ks], acc[ph * 2 + ii][j], 0, 0, 0);
      __builtin_amdgcn_s_setprio(0);
      if (ph == 1) {
        if (t == nt - 2) asm volatile("s_waitcnt vmcnt(0)" ::: "memory");
        else             asm volatile("s_waitcnt vmcnt(3)" ::: "memory");
      }
      QK_BARX();
    }
  }
#undef PAT
#undef PBT
#undef SEGL
#undef ST_A
#undef ST_B0
#undef ST_B123
}

// ---------------------------------------------------------------------------
// Output projection: out[4096,2048] fp32 = Ob x WtO^T. Grid 256 = 1 round.
__global__ __launch_bounds__(512, 2) void gemm_wo_kernel(
    const ushort_t* __restrict__ A, const ushort_t* __restrict__ Bt,
    float* __restrict__ out) {
  __shared__ char lds[98304];
  const int tid = (int)threadIdx.x;
  const int w = tid >> 6, lane = tid & 63, quad = lane >> 4, l15 = lane & 15;
  const int wr = (w >> 2) * 64, wc = (w & 3) * 64;

  const int wg = ((int)blockIdx.x & 7) * 32 + ((int)blockIdx.x >> 3);
  const size_t bm0 = (size_t)(wg & 31) * 128;
  const size_t bn0 = (size_t)(wg >> 5) * 256;

  f32x4 acc[4][4];
  f32x4 z4 = {0.f, 0.f, 0.f, 0.f};
#pragma unroll
  for (int i = 0; i < 4; ++i)
#pragma unroll
    for (int j = 0; j < 4; ++j) acc[i][j] = z4;

  kloop_128x256(lds, A, Bt, bm0, bn0, acc);

#pragma unroll
  for (int i = 0; i < 4; ++i)
#pragma unroll
    for (int r = 0; r < 4; ++r) {
      size_t m = bm0 + wr + i * 16 + quad * 4 + r;
#pragma unroll
      for (int j = 0; j < 4; ++j) {
        size_t n = bn0 + wc + j * 16 + l15;
        out[m * 2048 + n] = acc[i][j][r];
      }
    }
}

// ---------------------------------------------------------------------------
// Flash attention, causal, + fused adapter attention. (R8 structure.)
__global__ __launch_bounds__(256, 4) void flash_kernel(
    const ushort_t* __restrict__ Qb, const ushort_t* __restrict__ Kb,
    const ushort_t* __restrict__ Vt, const ushort_t* __restrict__ akb,
    const ushort_t* __restrict__ avb, const float* __restrict__ gate,
    ushort_t* __restrict__ Ob) {
  __shared__ char ldsK[16384];   // 64 tok x 256B, chunk swz ^(row&15)
  __shared__ char ldsV[16384];   // 128 d x 128B, chunk swz ^(dr&7)
  __shared__ char ldsP[8192];    // loop: P 64q x 128B swz; epilogue: pa[64][40]
  const int tid = threadIdx.x;
  const int w = tid >> 6, lane = tid & 63, quad = lane >> 4, l15 = lane & 15;
  const int idx = blockIdx.x;
  const int pg = idx >> 8, c = idx & 255;
  const int u = c >> 3, vv = c & 7;
  const int uu = (pg & 2) ? ((u + 16) & 31) : u;
  const int qt2 = (pg & 1) ? (31 - uu) : uu;     // 64-row q-tile index [0,32)
  const int hb = (pg << 3) | vv;                 // [0,32)
  const int h = hb >> 1, b = hb & 1;
  const float scale = 0.08838834764831845f;      // 1/sqrt(128)

  bf16x8 ones;
#pragma unroll
  for (int j = 0; j < 8; ++j) ones[j] = (short)0x3F80;

  bf16x8 qf[4];
  {
    size_t qrow = (size_t)qt2 * 64 + w * 16 + l15;
    const ushort_t* base = Qb + ((size_t)b * 2048 + qrow) * 2048 + h * 128 + quad * 8;
#pragma unroll
    for (int ds = 0; ds < 4; ++ds) qf[ds] = *(const bf16x8*)(base + ds * 32);
  }

  f32x4 zero4 = {0.f, 0.f, 0.f, 0.f};
  f32x4 oacc[8];
  f32x4 osum = zero4;
  float mrow[4];
#pragma unroll
  for (int n8 = 0; n8 < 8; ++n8) oacc[n8] = zero4;
#pragma unroll
  for (int r = 0; r < 4; ++r) mrow[r] = -1e30f;

  for (int kt = 0; kt <= qt2; ++kt) {
#pragma unroll
    for (int ii = 0; ii < 4; ++ii) {
      int r0 = w * 16 + ii * 4;
      int row = r0 + (lane >> 4);
      int cl = (lane & 15) ^ (row & 15);
      async16(ldsK + r0 * 256,
              Kb + ((size_t)b * 2048 + kt * 64 + row) * 2048 + h * 128 + cl * 8);
    }
#pragma unroll
    for (int ii = 0; ii < 4; ++ii) {
      int d0 = w * 32 + ii * 8;
      int dr = d0 + (lane >> 3);
      int cl = (lane & 7) ^ (dr & 7);
      async16(ldsV + d0 * 128,
              Vt + ((size_t)(b * 16 + h) * 128 + dr) * 2048 + kt * 64 + cl * 8);
    }
    __syncthreads();

    f32x4 sacc[4];
#pragma unroll
    for (int nt = 0; nt < 4; ++nt) sacc[nt] = zero4;
#pragma unroll
    for (int ds = 0; ds < 4; ++ds) {
      bf16x8 kf[4];
      int ch = ds * 4 + quad;
#pragma unroll
      for (int nt = 0; nt < 4; ++nt) {
        int row = nt * 16 + l15;
        kf[nt] = *(const bf16x8*)(ldsK + row * 256 + ((ch ^ (row & 15)) * 16));
      }
#pragma unroll
      for (int nt = 0; nt < 4; ++nt)
        sacc[nt] = __builtin_amdgcn_mfma_f32_16x16x32_bf16(qf[ds], kf[nt], sacc[nt], 0, 0, 0);
    }

    const bool domask = (kt == qt2);
    float tmax[4] = {-1e30f, -1e30f, -1e30f, -1e30f};
    const int qbr = qt2 * 64 + w * 16 + quad * 4;
#pragma unroll
    for (int nt = 0; nt < 4; ++nt) {
      int kg = kt * 64 + nt * 16 + l15;
#pragma unroll
      for (int r = 0; r < 4; ++r) {
        float s = sacc[nt][r] * scale;
        if (domask && kg > qbr + r) s = -1e30f;
        sacc[nt][r] = s;
        tmax[r] = fmaxf(tmax[r], s);
      }
    }
    float need = 0.f;
#pragma unroll
    for (int r = 0; r < 4; ++r) {
      tmax[r] = rowmax16(tmax[r]);
      need = fmaxf(need, tmax[r] - mrow[r]);
    }
    if (__any(need > 8.0f)) {
      float alpha[4];
#pragma unroll
      for (int r = 0; r < 4; ++r) {
        float mnew = fmaxf(mrow[r], tmax[r]);
        alpha[r] = __expf(mrow[r] - mnew);
        osum[r] *= alpha[r];
        mrow[r] = mnew;
      }
#pragma unroll
      for (int n8 = 0; n8 < 8; ++n8)
#pragma unroll
        for (int r = 0; r < 4; ++r) oacc[n8][r] *= alpha[r];
    }
    uint32 pk[4][4];
#pragma unroll
    for (int nt = 0; nt < 4; ++nt)
#pragma unroll
      for (int r = 0; r < 4; ++r) {
        float pv = __expf(sacc[nt][r] - mrow[r]);
        float pn = dpp_xor1(pv);
        uint32 d_;
        asm volatile("v_cvt_pk_bf16_f32 %0, %1, %2" : "=v"(d_) : "v"(pv), "v"(pn));
        pk[nt][r] = d_;
      }
    if (!(lane & 1)) {
#pragma unroll
      for (int nt = 0; nt < 4; ++nt)
#pragma unroll
        for (int r = 0; r < 4; ++r) {
          int col = nt * 16 + l15;   // even
          int prow = w * 16 + quad * 4 + r;
          *(uint32*)(ldsP + prow * 128 + (((col >> 3) ^ (prow & 7)) * 16) + (col & 7) * 2) = pk[nt][r];
        }
    }

#pragma unroll
    for (int ks = 0; ks < 2; ++ks) {
      int ch = ks * 4 + quad;
      int prow = w * 16 + l15;
      bf16x8 pf = *(const bf16x8*)(ldsP + prow * 128 + ((ch ^ (prow & 7)) * 16));
      osum = __builtin_amdgcn_mfma_f32_16x16x32_bf16(pf, ones, osum, 0, 0, 0);
#pragma unroll
      for (int n8 = 0; n8 < 8; ++n8) {
        int dr = n8 * 16 + l15;
        bf16x8 vf = *(const bf16x8*)(ldsV + dr * 128 + ((ch ^ (dr & 7)) * 16));
        oacc[n8] = __builtin_amdgcn_mfma_f32_16x16x32_bf16(pf, vf, oacc[n8], 0, 0, 0);
      }
    }
    __syncthreads();
  }

  // ---------------- fused adapter epilogue ----------------
  const float g = gate[h];
  {
    int row = w * 16 + (lane >> 2);
    *(uint2*)(ldsP + row * 80 + 32 + (lane & 3) * 8) = make_uint2(0, 0);
  }
  f32x4 sa = zero4;
#pragma unroll
  for (int ds = 0; ds < 4; ++ds) {
    bf16x8 kfa = *(const bf16x8*)(akb + ((size_t)h * 16 + l15) * 128 + ds * 32 + quad * 8);
    sa = __builtin_amdgcn_mfma_f32_16x16x32_bf16(qf[ds], kfa, sa, 0, 0, 0);
  }
#pragma unroll
  for (int r = 0; r < 4; ++r) {
    float s = sa[r] * scale;
    if (l15 >= 10) s = -1e30f;
    float mx = rowmax16(s);
    float e = __expf(s - mx);
    float sum = rowsum16(e);
    float pv = g * e / sum;
    int row = w * 16 + quad * 4 + r;
    *(ushort_t*)(ldsP + row * 80 + l15 * 2) = f2bf(pv);
  }
  bf16x8 paf = *(const bf16x8*)(ldsP + (w * 16 + l15) * 80 + quad * 16);

  float rl[4];
#pragma unroll
  for (int r = 0; r < 4; ++r) rl[r] = 1.f / osum[r];
#pragma unroll
  for (int n8 = 0; n8 < 8; ++n8)
#pragma unroll
    for (int r = 0; r < 4; ++r) oacc[n8][r] *= rl[r];
#pragma unroll
  for (int n8 = 0; n8 < 8; ++n8) {
    bf16x8 avf = *(const bf16x8*)(avb + ((size_t)h * 128 + n8 * 16 + l15) * 32 + quad * 8);
    oacc[n8] = __builtin_amdgcn_mfma_f32_16x16x32_bf16(paf, avf, oacc[n8], 0, 0, 0);
  }
  size_t qb0 = (size_t)qt2 * 64 + w * 16 + quad * 4;
#pragma unroll
  for (int n8 = 0; n8 < 8; ++n8) {
    size_t col = (size_t)h * 128 + n8 * 16 + l15;
#pragma unroll
    for (int r = 0; r < 4; ++r)
      Ob[((size_t)b * 2048 + qb0 + r) * 2048 + col] = f2bf(oacc[n8][r]);
  }
}

// ---------------------------------------------------------------------------
extern "C" void kernel_launch(void* const* d_in, const int* in_sizes, int n_in,
                              void* d_out, int out_size, void* d_ws, size_t ws_size,
                              hipStream_t stream) {
  (void)in_sizes; (void)n_in; (void)out_size; (void)ws_size;
  const float* x       = (const float*)d_in[0];
  const float* wq      = (const float*)d_in[1];
  const float* wk      = (const float*)d_in[2];
  const float* wv      = (const float*)d_in[3];
  const float* wo      = (const float*)d_in[4];
  const float* adapter = (const float*)d_in[5];
  const float* gate    = (const float*)d_in[6];
  const float* fc      = (const float*)d_in[7];
  const float* fs      = (const float*)d_in[8];

  char* ws = (char*)d_ws;
  ushort_t* Xb   = (ushort_t*)(ws + 0);           // 16 MB (reused as Ob)
  ushort_t* WtQ  = (ushort_t*)(ws + 16777216);    // 8 MB x4 contiguous
  ushort_t* WtO  = (ushort_t*)(ws + 41943040);
  ushort_t* Qb   = (ushort_t*)(ws + 50331648);    // 16 MB
  ushort_t* Kb   = (ushort_t*)(ws + 67108864);    // 16 MB
  ushort_t* Vt   = (ushort_t*)(ws + 83886080);    // 16 MB
  float*    ak   = (float*)   (ws + 100663296);   // 80 KB
  float*    av   = (float*)   (ws + 100745216);   // 80 KB
  ushort_t* akb  = (ushort_t*)(ws + 100827136);   // 64 KB
  ushort_t* avb  = (ushort_t*)(ws + 100892672);   // 128 KB
  ushort_t* Ob   = Xb;

  cast_x_kernel<<<4096, 256, 0, stream>>>(x, Xb);
  transpose_w_kernel<<<dim3(32, 32, 4), 256, 0, stream>>>(wq, wk, wv, wo, WtQ);
  hipMemsetAsync(ak, 0, 163840, stream);
  adapter_kv_kernel<<<dim3(8, 16, 2), 256, 0, stream>>>(adapter, wk, wv, ak, av);
  adapter_pack_kernel<<<256, 256, 0, stream>>>(ak, av, akb, avb);
  gemm_qkv256_kernel<<<dim3(384), 512, 0, stream>>>(Xb, WtQ, Qb, Kb, Vt, fc, fs);
  flash_kernel<<<dim3(1024), 256, 0, stream>>>(Qb, Kb, Vt, akb, avb, gate, Ob);
  gemm_wo_kernel<<<dim3(256), 512, 0, stream>>>(Ob, WtO, (float*)d_out);
}

// Round 7
// 426.574 us; speedup vs baseline: 1.9100x; 1.0339x over previous
//
#include <hip/hip_runtime.h>

// ---------------------------------------------------------------------------
// Attention_16698832847178: B=2,S=2048,D=2048,H=16,HD=128,L=10
// R12: GEMM tile-size lever exhausted (256^2 per-block gain == packing tax);
// qkv reverted to R8's proven 128x256 kloop (123.4us). Flash rebuilt as
// R7 geometry (128q/block, 4 waves x 32 rows => half the LDS bytes/FLOP of
// the 64q version; flash is LDS-BW-bound) + R8's softmax wins (defer-max
// THR=8, dpp+v_cvt_pk_bf16_f32 packed P-store). Grid 512, LDS 48KB.
// ---------------------------------------------------------------------------

typedef unsigned short ushort_t;
typedef unsigned int uint32;
typedef __attribute__((ext_vector_type(8))) short bf16x8;   // 8 bf16 = 4 VGPRs
typedef __attribute__((ext_vector_type(4))) float f32x4;

__device__ __forceinline__ void async16(void* lds, const void* g) {
  __builtin_amdgcn_global_load_lds((const __attribute__((address_space(1))) void*)g,
                                   (__attribute__((address_space(3))) void*)lds,
                                   16, 0, 0);
}
__device__ __forceinline__ ushort_t f2bf(float f) {
  uint32 u = __float_as_uint(f);
  u += 0x7FFFu + ((u >> 16) & 1u);   // round-to-nearest-even
  return (ushort_t)(u >> 16);
}
__device__ __forceinline__ float bf2f(ushort_t b) {
  return __uint_as_float(((uint32)b) << 16);
}
// value from lane^1 via DPP quad_perm [1,0,3,2] (VALU, no LDS)
__device__ __forceinline__ float dpp_xor1(float v) {
  return __int_as_float(__builtin_amdgcn_update_dpp(
      0, __float_as_int(v), 0xB1, 0xf, 0xf, true));
}
#define DPP_MAX(t, ctrl) \
  t = fmaxf(t, __int_as_float(__builtin_amdgcn_update_dpp( \
      0, __float_as_int(t), (ctrl), 0xf, 0xf, true)))
#define DPP_ADD(t, ctrl) \
  t += __int_as_float(__builtin_amdgcn_update_dpp( \
      0, __float_as_int(t), (ctrl), 0xf, 0xf, true))
__device__ __forceinline__ float rowmax16(float t) {
  DPP_MAX(t, 0xB1);   // xor 1
  DPP_MAX(t, 0x4E);   // xor 2
  t = fmaxf(t, __int_as_float(__builtin_amdgcn_ds_swizzle(
      __float_as_int(t), 0x101F)));                  // xor 4
  DPP_MAX(t, 0x128);  // row_ror:8 -> xor 8 (halves uniform after xor1/2/4)
  return t;
}
__device__ __forceinline__ float rowsum16(float t) {
  DPP_ADD(t, 0xB1);
  DPP_ADD(t, 0x4E);
  t += __int_as_float(__builtin_amdgcn_ds_swizzle(__float_as_int(t), 0x101F));
  DPP_ADD(t, 0x128);
  return t;
}

// ---------------------------------------------------------------------------
// cast x (fp32) -> bf16, 8 elements/thread
__global__ __launch_bounds__(256) void cast_x_kernel(const float* __restrict__ x,
                                                     ushort_t* __restrict__ Xb) {
  size_t i = ((size_t)blockIdx.x * 256 + threadIdx.x) * 8;
  float4 a = *(const float4*)(x + i);
  float4 b = *(const float4*)(x + i + 4);
  uint4 o;
  o.x = (uint32)f2bf(a.x) | ((uint32)f2bf(a.y) << 16);
  o.y = (uint32)f2bf(a.z) | ((uint32)f2bf(a.w) << 16);
  o.z = (uint32)f2bf(b.x) | ((uint32)f2bf(b.y) << 16);
  o.w = (uint32)f2bf(b.z) | ((uint32)f2bf(b.w) << 16);
  *(uint4*)(Xb + i) = o;
}

// ---------------------------------------------------------------------------
// W[k][n] fp32 -> Wt[n][k] bf16 (64x64 tiles), dword stores
__global__ __launch_bounds__(256) void transpose_w_kernel(
    const float* __restrict__ w0, const float* __restrict__ w1,
    const float* __restrict__ w2, const float* __restrict__ w3,
    ushort_t* __restrict__ outBase) {
  const float* W = (blockIdx.z == 0) ? w0 : (blockIdx.z == 1) ? w1
                 : (blockIdx.z == 2) ? w2 : w3;
  ushort_t* Wt = outBase + (size_t)blockIdx.z * 4194304;  // 2048*2048
  __shared__ float L[64][65];
  int t = threadIdx.x, tc = t & 63, tr = t >> 6;
  int k0 = blockIdx.x * 64, n0 = blockIdx.y * 64;
  for (int i = 0; i < 16; ++i) {
    int r = i * 4 + tr;
    L[r][tc] = W[(size_t)(k0 + r) * 2048 + n0 + tc];
  }
  __syncthreads();
  int tr8 = t >> 5, tc2 = t & 31;
  for (int i = 0; i < 8; ++i) {
    int r = i * 8 + tr8;
    uint32 pk = (uint32)f2bf(L[2 * tc2][r]) | ((uint32)f2bf(L[2 * tc2 + 1][r]) << 16);
    *(uint32*)(Wt + (size_t)(n0 + r) * 2048 + k0 + 2 * tc2) = pk;
  }
}

// ---------------------------------------------------------------------------
// adapter projections: ak/av[l][n] = sum_k adapter[l][k] * W[k][n]  (fp32)
__global__ __launch_bounds__(256) void adapter_kv_kernel(
    const float* __restrict__ adapter, const float* __restrict__ wk,
    const float* __restrict__ wv, float* __restrict__ ak, float* __restrict__ av) {
  const float* W = blockIdx.z ? wv : wk;
  float* out = blockIdx.z ? av : ak;
  __shared__ float As[10][128];
  int t = threadIdx.x;
  int k0 = blockIdx.y * 128;
  for (int i = t; i < 1280; i += 256)
    As[i >> 7][i & 127] = adapter[(size_t)(i >> 7) * 2048 + k0 + (i & 127)];
  __syncthreads();
  int n = blockIdx.x * 256 + t;
  float acc[10];
#pragma unroll
  for (int l = 0; l < 10; ++l) acc[l] = 0.f;
  for (int kk = 0; kk < 128; ++kk) {
    float wv_ = W[(size_t)(k0 + kk) * 2048 + n];
#pragma unroll
    for (int l = 0; l < 10; ++l) acc[l] += As[l][kk] * wv_;
  }
#pragma unroll
  for (int l = 0; l < 10; ++l) atomicAdd(&out[l * 2048 + n], acc[l]);
}

// ---------------------------------------------------------------------------
// pack ak/av (fp32) into MFMA-fragment-friendly bf16 buffers:
// akb[h][l(16)][d(128)] (l>=10 zero), avb[h][d(128)][l(32)] (l>=10 zero)
__global__ __launch_bounds__(256) void adapter_pack_kernel(
    const float* __restrict__ ak, const float* __restrict__ av,
    ushort_t* __restrict__ akb, ushort_t* __restrict__ avb) {
  int t = blockIdx.x * 256 + threadIdx.x;   // 65536 threads
  if (t < 32768) {
    int h = t >> 11, l = (t >> 7) & 15, d = t & 127;
    akb[t] = (l < 10) ? f2bf(ak[l * 2048 + h * 128 + d]) : (ushort_t)0;
  }
  int h = t >> 12, d = (t >> 5) & 127, l = t & 31;
  avb[t] = (l < 10) ? f2bf(av[l * 2048 + h * 128 + d]) : (ushort_t)0;
}

#define QK_BARX() asm volatile("s_barrier" ::: "memory")
#define QK_LGKM0() asm volatile("s_waitcnt lgkmcnt(0)" ::: "memory")

// ---------------------------------------------------------------------------
// R8's proven pipelined 128x256 K-loop (A and B in LDS).
__device__ __forceinline__ void kloop_128x256(
    char* lds, const ushort_t* __restrict__ A, const ushort_t* __restrict__ Bt,
    size_t bm0, size_t bn0, f32x4 (&acc)[4][4]) {
  const int tid = (int)threadIdx.x;
  const int w = tid >> 6, lane = tid & 63, quad = lane >> 4, l15 = lane & 15;
  const int wr = (w >> 2) * 64, wc = (w & 3) * 64;
  const int nt = 32;
  char* const pA0 = lds;
  char* const pA1 = lds + 16384;
  char* const pB0 = lds + 32768;
  char* const pB1 = lds + 65536;

#define PAT(T) (((T) & 1) ? pA1 : pA0)
#define PBT(T) (((T) & 1) ? pB1 : pB0)
#define SEGL(OP, LDSB, GROW, T)                                                \
  do {                                                                         \
    int rr_ = w * 8 + (lane >> 3);                                             \
    int cl_ = (lane & 7) ^ (rr_ & 7);                                          \
    async16((LDSB) + w * 1024,                                                 \
            (OP) + ((GROW) + (size_t)rr_) * 2048 + (size_t)((T) * 64 + cl_ * 8)); \
  } while (0)
#define ST_A(T)                                                                \
  do { if ((T) < nt) { SEGL(A, PAT(T), bm0, (T));                              \
                       SEGL(A, PAT(T) + 8192, bm0 + 64, (T)); } } while (0)
#define ST_B0(T)                                                               \
  do { if ((T) < nt) SEGL(Bt, PBT(T), bn0, (T)); } while (0)
#define ST_B123(T)                                                             \
  do { if ((T) < nt) { SEGL(Bt, PBT(T) + 8192,  bn0 + 64,  (T));               \
                       SEGL(Bt, PBT(T) + 16384, bn0 + 128, (T));               \
                       SEGL(Bt, PBT(T) + 24576, bn0 + 192, (T)); } } while (0)

  ST_A(0); ST_B0(0); ST_B123(0); ST_B123(1);
  asm volatile("s_waitcnt vmcnt(3)" ::: "memory");
  QK_BARX();

#pragma unroll 2
  for (int t = 0; t < nt; ++t) {
    const char* pA = PAT(t);
    const char* pB = PBT(t);
    bf16x8 bfv[4][2];
#pragma unroll
    for (int j = 0; j < 4; ++j) {
      int brow = wc + j * 16 + l15;
#pragma unroll
      for (int ks = 0; ks < 2; ++ks)
        bfv[j][ks] = *(const bf16x8*)(pB + brow * 128 +
                                      (((ks * 4 + quad) ^ (brow & 7)) * 16));
    }
#pragma unroll
    for (int ph = 0; ph < 2; ++ph) {
      bf16x8 af[2][2];
#pragma unroll
      for (int ii = 0; ii < 2; ++ii) {
        int arow = wr + (ph * 2 + ii) * 16 + l15;
#pragma unroll
        for (int ks = 0; ks < 2; ++ks)
          af[ii][ks] = *(const bf16x8*)(pA + arow * 128 +
                                        (((ks * 4 + quad) ^ (arow & 7)) * 16));
      }
      if (ph == 0) { ST_A(t + 1); ST_B0(t + 1); }
      else         { ST_B123(t + 2); }
      QK_BARX();
      QK_LGKM0();
      __builtin_amdgcn_s_setprio(1);
#pragma unroll
      for (int ks = 0; ks < 2; ++ks)
#pragma unroll
        for (int ii = 0; ii < 2; ++ii)
#pragma unroll
          for (int j = 0; j < 4; ++j)
            acc[ph * 2 + ii][j] = __builtin_amdgcn_mfma_f32_16x16x32_bf16(
                af[ii][ks], bfv[j][ks], acc[ph * 2 + ii][j], 0, 0, 0);
      __builtin_amdgcn_s_setprio(0);
      if (ph == 1) {
        if (t == nt - 2) asm volatile("s_waitcnt vmcnt(0)" ::: "memory");
        else             asm volatile("s_waitcnt vmcnt(3)" ::: "memory");
      }
      QK_BARX();
    }
  }
#undef PAT
#undef PBT
#undef SEGL
#undef ST_A
#undef ST_B0
#undef ST_B123
}

// ---------------------------------------------------------------------------
// Fused QKV GEMM: C[4096,6144] = Xb[4096,2048] x WtQKV[6144,2048]^T.
// Grid 768 (32 M x 24 N) = exactly 3 rounds of 256 CUs. (R8 kernel.)
__global__ __launch_bounds__(512, 2) void gemm_qkv128_kernel(
    const ushort_t* __restrict__ A, const ushort_t* __restrict__ Bt,
    ushort_t* __restrict__ outQ, ushort_t* __restrict__ outK,
    ushort_t* __restrict__ Vt,
    const float* __restrict__ fc, const float* __restrict__ fs) {
  __shared__ char lds[98304];
  const int tid = (int)threadIdx.x;
  const int w = tid >> 6, lane = tid & 63, quad = lane >> 4, l15 = lane & 15;
  const int wr = (w >> 2) * 64, wc = (w & 3) * 64;

  const int wg = ((int)blockIdx.x & 7) * 96 + ((int)blockIdx.x >> 3);
  const size_t bm0 = (size_t)(wg & 31) * 128;
  const size_t bn0 = (size_t)(wg >> 5) * 256;

  f32x4 acc[4][4];
  f32x4 z4 = {0.f, 0.f, 0.f, 0.f};
#pragma unroll
  for (int i = 0; i < 4; ++i)
#pragma unroll
    for (int j = 0; j < 4; ++j) acc[i][j] = z4;

  kloop_128x256(lds, A, Bt, bm0, bn0, acc);

  const int seg = (int)(bn0 >> 11);   // 0=Q, 1=K, 2=V
  if (seg < 2) {
    ushort_t* ob = seg ? outK : outQ;
#pragma unroll
    for (int i = 0; i < 4; ++i)
#pragma unroll
      for (int r = 0; r < 4; ++r) {
        size_t m = bm0 + wr + i * 16 + quad * 4 + r;
        int s = (int)(m & 2047);
#pragma unroll
        for (int j = 0; j < 4; ++j) {
          size_t n = (bn0 + wc + j * 16 + l15) & 2047;
          float v = acc[i][j][r];
          float v2 = dpp_xor1(v);             // RoPE pair partner (col n^1)
          int fi = ((int)n & 127) >> 1;
          float cosv = fc[s * 64 + fi];
          float sinv = fs[s * 64 + fi];
          v = (lane & 1) ? (v2 * sinv + v * cosv) : (v * cosv - v2 * sinv);
          ob[m * 2048 + n] = f2bf(v);
        }
      }
  } else {
    // V segment: per-wave 64(n) x 64(m) transpose patch through LDS.
    char* T = lds + w * 8192;
#pragma unroll
    for (int i = 0; i < 4; ++i)
#pragma unroll
      for (int j = 0; j < 4; ++j) {
        int nn = j * 16 + l15;
        int md0 = i * 8 + quad * 2;
        uint32 p01 = (uint32)f2bf(acc[i][j][0]) | ((uint32)f2bf(acc[i][j][1]) << 16);
        uint32 p23 = (uint32)f2bf(acc[i][j][2]) | ((uint32)f2bf(acc[i][j][3]) << 16);
        *(uint32*)(T + nn * 128 + ((md0 ^ (nn & 31)) * 4)) = p01;
        *(uint32*)(T + nn * 128 + (((md0 + 1) ^ (nn & 31)) * 4)) = p23;
      }
    const int b = (int)(bm0 >> 11);
    const int s0 = (int)(bm0 & 2047) + wr;
    const int n2 = (int)(bn0 & 2047) + wc;
#pragma unroll
    for (int it = 0; it < 32; ++it) {
      int row = it * 2 + (lane >> 5);
      int pp = lane & 31;
      uint32 dv = *(const uint32*)(T + row * 128 + pp * 4);
      int md = pp ^ (row & 31);
      int nloc = n2 + row;
      size_t bh = (size_t)b * 16 + (nloc >> 7);
      *(uint32*)(Vt + (bh * 128 + (size_t)(nloc & 127)) * 2048 + s0 + 2 * md) = dv;
    }
  }
}

// ---------------------------------------------------------------------------
// Output projection: out[4096,2048] fp32 = Ob x WtO^T. Grid 256 = 1 round.
__global__ __launch_bounds__(512, 2) void gemm_wo_kernel(
    const ushort_t* __restrict__ A, const ushort_t* __restrict__ Bt,
    float* __restrict__ out) {
  __shared__ char lds[98304];
  const int tid = (int)threadIdx.x;
  const int w = tid >> 6, lane = tid & 63, quad = lane >> 4, l15 = lane & 15;
  const int wr = (w >> 2) * 64, wc = (w & 3) * 64;

  const int wg = ((int)blockIdx.x & 7) * 32 + ((int)blockIdx.x >> 3);
  const size_t bm0 = (size_t)(wg & 31) * 128;
  const size_t bn0 = (size_t)(wg >> 5) * 256;

  f32x4 acc[4][4];
  f32x4 z4 = {0.f, 0.f, 0.f, 0.f};
#pragma unroll
  for (int i = 0; i < 4; ++i)
#pragma unroll
    for (int j = 0; j < 4; ++j) acc[i][j] = z4;

  kloop_128x256(lds, A, Bt, bm0, bn0, acc);

#pragma unroll
  for (int i = 0; i < 4; ++i)
#pragma unroll
    for (int r = 0; r < 4; ++r) {
      size_t m = bm0 + wr + i * 16 + quad * 4 + r;
#pragma unroll
      for (int j = 0; j < 4; ++j) {
        size_t n = bn0 + wc + j * 16 + l15;
        out[m * 2048 + n] = acc[i][j][r];
      }
    }
}

// ---------------------------------------------------------------------------
// Flash attention, causal, + fused adapter attention.
// R12: 128 q-rows/block (4 waves x 32 rows, mt=2) = half the LDS bytes/FLOP
// of the 64q version (flash is LDS-BW-bound), with R8's defer-max (THR=8)
// and dpp+cvt_pk packed P-store. Grid 512, LDS 48KB, balanced {u,15-u}.
__global__ __launch_bounds__(256) void flash_kernel(
    const ushort_t* __restrict__ Qb, const ushort_t* __restrict__ Kb,
    const ushort_t* __restrict__ Vt, const ushort_t* __restrict__ akb,
    const ushort_t* __restrict__ avb, const float* __restrict__ gate,
    ushort_t* __restrict__ Ob) {
  __shared__ char ldsK[16384];   // 64 tok x 256B, chunk swz ^(row&15)
  __shared__ char ldsV[16384];   // 128 d x 128B, chunk swz ^(dr&7)
  __shared__ char ldsP[16384];   // loop: P 128q x 128B swz; epilogue: pa[128][40]
  const int tid = threadIdx.x;
  const int w = tid >> 6, lane = tid & 63, quad = lane >> 4, l15 = lane & 15;
  const int idx = blockIdx.x;
  const int p = idx >> 8, c = idx & 255;
  const int u = c >> 4, vv = c & 15;
  const int qt = p ? (15 - u) : u;
  const int hb = (p << 4) | vv;
  const int h = hb >> 1, b = hb & 1;
  const float scale = 0.08838834764831845f;  // 1/sqrt(128)

  bf16x8 ones;
#pragma unroll
  for (int j = 0; j < 8; ++j) ones[j] = (short)0x3F80;

  // Q fragments in registers: 2 m-tiles x 4 d-steps (wave rows w*32..+31)
  bf16x8 qf[2][4];
#pragma unroll
  for (int mt = 0; mt < 2; ++mt) {
    size_t qrow = (size_t)qt * 128 + w * 32 + mt * 16 + l15;
    const ushort_t* base = Qb + ((size_t)b * 2048 + qrow) * 2048 + h * 128 + quad * 8;
#pragma unroll
    for (int ds = 0; ds < 4; ++ds) qf[mt][ds] = *(const bf16x8*)(base + ds * 32);
  }

  f32x4 zero4 = {0.f, 0.f, 0.f, 0.f};
  f32x4 oacc[2][8];
  f32x4 osum[2];
  float mrow[2][4];
#pragma unroll
  for (int mt = 0; mt < 2; ++mt) {
#pragma unroll
    for (int n8 = 0; n8 < 8; ++n8) oacc[mt][n8] = zero4;
    osum[mt] = zero4;
#pragma unroll
    for (int r = 0; r < 4; ++r) mrow[mt][r] = -1e30f;
  }

  const int ktmax = 2 * qt + 1;
  for (int kt = 0; kt <= ktmax; ++kt) {
#pragma unroll
    for (int ii = 0; ii < 4; ++ii) {
      int r0 = w * 16 + ii * 4;
      int row = r0 + (lane >> 4);
      int cl = (lane & 15) ^ (row & 15);
      async16(ldsK + r0 * 256,
              Kb + ((size_t)b * 2048 + kt * 64 + row) * 2048 + h * 128 + cl * 8);
    }
#pragma unroll
    for (int ii = 0; ii < 4; ++ii) {
      int d0 = w * 32 + ii * 8;
      int dr = d0 + (lane >> 3);
      int cl = (lane & 7) ^ (dr & 7);
      async16(ldsV + d0 * 128,
              Vt + ((size_t)(b * 16 + h) * 128 + dr) * 2048 + kt * 64 + cl * 8);
    }
    __syncthreads();

    // S = Q K^T
    f32x4 sacc[2][4];
#pragma unroll
    for (int mt = 0; mt < 2; ++mt)
#pragma unroll
      for (int nt = 0; nt < 4; ++nt) sacc[mt][nt] = zero4;
#pragma unroll
    for (int ds = 0; ds < 4; ++ds) {
      bf16x8 kf[4];
      int ch = ds * 4 + quad;
#pragma unroll
      for (int nt = 0; nt < 4; ++nt) {
        int row = nt * 16 + l15;
        kf[nt] = *(const bf16x8*)(ldsK + row * 256 + ((ch ^ (row & 15)) * 16));
      }
#pragma unroll
      for (int mt = 0; mt < 2; ++mt)
#pragma unroll
        for (int nt = 0; nt < 4; ++nt)
          sacc[mt][nt] = __builtin_amdgcn_mfma_f32_16x16x32_bf16(qf[mt][ds], kf[nt], sacc[mt][nt], 0, 0, 0);
    }

    // online softmax (defer-max, THR=8)
    const bool domask = (kt >= 2 * qt);
    float tmax2[2][4];
    float need = 0.f;
#pragma unroll
    for (int mt = 0; mt < 2; ++mt) {
      float tmax[4] = {-1e30f, -1e30f, -1e30f, -1e30f};
      const int qbase = qt * 128 + w * 32 + mt * 16 + quad * 4;
#pragma unroll
      for (int nt = 0; nt < 4; ++nt) {
        int kg = kt * 64 + nt * 16 + l15;
#pragma unroll
        for (int r = 0; r < 4; ++r) {
          float s = sacc[mt][nt][r] * scale;
          if (domask && kg > qbase + r) s = -1e30f;
          sacc[mt][nt][r] = s;
          tmax[r] = fmaxf(tmax[r], s);
        }
      }
#pragma unroll
      for (int r = 0; r < 4; ++r) {
        tmax2[mt][r] = rowmax16(tmax[r]);
        need = fmaxf(need, tmax2[mt][r] - mrow[mt][r]);
      }
    }
    if (__any(need > 8.0f)) {
#pragma unroll
      for (int mt = 0; mt < 2; ++mt) {
        float alpha[4];
#pragma unroll
        for (int r = 0; r < 4; ++r) {
          float mnew = fmaxf(mrow[mt][r], tmax2[mt][r]);
          alpha[r] = __expf(mrow[mt][r] - mnew);
          osum[mt][r] *= alpha[r];
          mrow[mt][r] = mnew;
        }
#pragma unroll
        for (int n8 = 0; n8 < 8; ++n8)
#pragma unroll
          for (int r = 0; r < 4; ++r) oacc[mt][n8][r] *= alpha[r];
      }
    }
    // P = exp(s - mrow); pack col pairs (l, l^1) via dpp + cvt_pk, even lanes
    // store dwords into swizzled ldsP.
#pragma unroll
    for (int mt = 0; mt < 2; ++mt) {
      uint32 pk[4][4];
#pragma unroll
      for (int nt = 0; nt < 4; ++nt)
#pragma unroll
        for (int r = 0; r < 4; ++r) {
          float pv = __expf(sacc[mt][nt][r] - mrow[mt][r]);
          float pn = dpp_xor1(pv);
          uint32 d_;
          asm volatile("v_cvt_pk_bf16_f32 %0, %1, %2" : "=v"(d_) : "v"(pv), "v"(pn));
          pk[nt][r] = d_;
        }
      if (!(lane & 1)) {
#pragma unroll
        for (int nt = 0; nt < 4; ++nt)
#pragma unroll
          for (int r = 0; r < 4; ++r) {
            int col = nt * 16 + l15;   // even
            int prow = w * 32 + mt * 16 + quad * 4 + r;
            *(uint32*)(ldsP + prow * 128 + (((col >> 3) ^ (prow & 7)) * 16) + (col & 7) * 2) = pk[nt][r];
          }
      }
    }

    // O += P V ; osum += P 1
#pragma unroll
    for (int ks = 0; ks < 2; ++ks) {
      int ch = ks * 4 + quad;
      bf16x8 pf[2];
#pragma unroll
      for (int mt = 0; mt < 2; ++mt) {
        int prow = w * 32 + mt * 16 + l15;
        pf[mt] = *(const bf16x8*)(ldsP + prow * 128 + ((ch ^ (prow & 7)) * 16));
      }
#pragma unroll
      for (int mt = 0; mt < 2; ++mt)
        osum[mt] = __builtin_amdgcn_mfma_f32_16x16x32_bf16(pf[mt], ones, osum[mt], 0, 0, 0);
#pragma unroll
      for (int n8 = 0; n8 < 8; ++n8) {
        int dr = n8 * 16 + l15;
        bf16x8 vf = *(const bf16x8*)(ldsV + dr * 128 + ((ch ^ (dr & 7)) * 16));
#pragma unroll
        for (int mt = 0; mt < 2; ++mt)
          oacc[mt][n8] = __builtin_amdgcn_mfma_f32_16x16x32_bf16(pf[mt], vf, oacc[mt][n8], 0, 0, 0);
      }
    }
    __syncthreads();
  }

  // ---------------- fused adapter epilogue ----------------
  const float g = gate[h];
  {
    int row = w * 32 + (lane >> 1);
    int koff = 16 + (lane & 1) * 8;
    *(uint4*)(ldsP + row * 80 + koff * 2) = make_uint4(0, 0, 0, 0);
  }
  f32x4 zero4b = {0.f, 0.f, 0.f, 0.f};
  f32x4 sa[2] = {zero4b, zero4b};
#pragma unroll
  for (int ds = 0; ds < 4; ++ds) {
    bf16x8 kfa = *(const bf16x8*)(akb + ((size_t)h * 16 + l15) * 128 + ds * 32 + quad * 8);
#pragma unroll
    for (int mt = 0; mt < 2; ++mt)
      sa[mt] = __builtin_amdgcn_mfma_f32_16x16x32_bf16(qf[mt][ds], kfa, sa[mt], 0, 0, 0);
  }
#pragma unroll
  for (int mt = 0; mt < 2; ++mt) {
#pragma unroll
    for (int r = 0; r < 4; ++r) {
      float s = sa[mt][r] * scale;
      if (l15 >= 10) s = -1e30f;
      float mx = rowmax16(s);
      float e = __expf(s - mx);
      float sum = rowsum16(e);
      float pv = g * e / sum;
      int row = w * 32 + mt * 16 + quad * 4 + r;
      *(ushort_t*)(ldsP + row * 80 + l15 * 2) = f2bf(pv);
    }
  }
  bf16x8 paf[2];
#pragma unroll
  for (int mt = 0; mt < 2; ++mt)
    paf[mt] = *(const bf16x8*)(ldsP + (w * 32 + mt * 16 + l15) * 80 + quad * 16);

  // normalize main attention
#pragma unroll
  for (int mt = 0; mt < 2; ++mt) {
    float rl[4];
#pragma unroll
    for (int r = 0; r < 4; ++r) rl[r] = 1.f / osum[mt][r];
#pragma unroll
    for (int n8 = 0; n8 < 8; ++n8)
#pragma unroll
      for (int r = 0; r < 4; ++r) oacc[mt][n8][r] *= rl[r];
  }
  // += pa @ avb ; store bf16
#pragma unroll
  for (int n8 = 0; n8 < 8; ++n8) {
    bf16x8 avf = *(const bf16x8*)(avb + ((size_t)h * 128 + n8 * 16 + l15) * 32 + quad * 8);
#pragma unroll
    for (int mt = 0; mt < 2; ++mt)
      oacc[mt][n8] = __builtin_amdgcn_mfma_f32_16x16x32_bf16(paf[mt], avf, oacc[mt][n8], 0, 0, 0);
  }
#pragma unroll
  for (int mt = 0; mt < 2; ++mt) {
    size_t qb0 = (size_t)qt * 128 + w * 32 + mt * 16 + quad * 4;
#pragma unroll
    for (int n8 = 0; n8 < 8; ++n8) {
      size_t col = (size_t)h * 128 + n8 * 16 + l15;
#pragma unroll
      for (int r = 0; r < 4; ++r)
        Ob[((size_t)b * 2048 + qb0 + r) * 2048 + col] = f2bf(oacc[mt][n8][r]);
    }
  }
}

// ---------------------------------------------------------------------------
extern "C" void kernel_launch(void* const* d_in, const int* in_sizes, int n_in,
                              void* d_out, int out_size, void* d_ws, size_t ws_size,
                              hipStream_t stream) {
  (void)in_sizes; (void)n_in; (void)out_size; (void)ws_size;
  const float* x       = (const float*)d_in[0];
  const float* wq      = (const float*)d_in[1];
  const float* wk      = (const float*)d_in[2];
  const float* wv      = (const float*)d_in[3];
  const float* wo      = (const float*)d_in[4];
  const float* adapter = (const float*)d_in[5];
  const float* gate    = (const float*)d_in[6];
  const float* fc      = (const float*)d_in[7];
  const float* fs      = (const float*)d_in[8];

  char* ws = (char*)d_ws;
  ushort_t* Xb   = (ushort_t*)(ws + 0);           // 16 MB (reused as Ob)
  ushort_t* WtQ  = (ushort_t*)(ws + 16777216);    // 8 MB x4 contiguous
  ushort_t* WtO  = (ushort_t*)(ws + 41943040);
  ushort_t* Qb   = (ushort_t*)(ws + 50331648);    // 16 MB
  ushort_t* Kb   = (ushort_t*)(ws + 67108864);    // 16 MB
  ushort_t* Vt   = (ushort_t*)(ws + 83886080);    // 16 MB
  float*    ak   = (float*)   (ws + 100663296);   // 80 KB
  float*    av   = (float*)   (ws + 100745216);   // 80 KB
  ushort_t* akb  = (ushort_t*)(ws + 100827136);   // 64 KB
  ushort_t* avb  = (ushort_t*)(ws + 100892672);   // 128 KB
  ushort_t* Ob   = Xb;

  cast_x_kernel<<<4096, 256, 0, stream>>>(x, Xb);
  transpose_w_kernel<<<dim3(32, 32, 4), 256, 0, stream>>>(wq, wk, wv, wo, WtQ);
  hipMemsetAsync(ak, 0, 163840, stream);
  adapter_kv_kernel<<<dim3(8, 16, 2), 256, 0, stream>>>(adapter, wk, wv, ak, av);
  adapter_pack_kernel<<<256, 256, 0, stream>>>(ak, av, akb, avb);
  gemm_qkv128_kernel<<<dim3(768), 512, 0, stream>>>(Xb, WtQ, Qb, Kb, Vt, fc, fs);
  flash_kernel<<<dim3(512), 256, 0, stream>>>(Qb, Kb, Vt, akb, avb, gate, Ob);
  gemm_wo_kernel<<<dim3(256), 512, 0, stream>>>(Ob, WtO, (float*)d_out);
}

// Round 8
// 421.306 us; speedup vs baseline: 1.9339x; 1.0125x over previous
//
#include <hip/hip_runtime.h>

// ---------------------------------------------------------------------------
// Attention_16698832847178: B=2,S=2048,D=2048,H=16,HD=128,L=10
// R13: flash K/V staging double-buffered (stage kt+1 during compute of kt,
// counted vmcnt(8), raw barriers) -- removes per-k-tile exposed load latency.
// LDS 48->80KB (free: only 2 blocks/CU resident at grid 512). cast_x +
// transpose_w + adapter_kv merged into one prep_kernel (grid 8448) to cut
// 2 dispatch gaps. GEMMs unchanged from R12 (proven 128x256 kloop).
// ---------------------------------------------------------------------------

typedef unsigned short ushort_t;
typedef unsigned int uint32;
typedef __attribute__((ext_vector_type(8))) short bf16x8;   // 8 bf16 = 4 VGPRs
typedef __attribute__((ext_vector_type(4))) float f32x4;

__device__ __forceinline__ void async16(void* lds, const void* g) {
  __builtin_amdgcn_global_load_lds((const __attribute__((address_space(1))) void*)g,
                                   (__attribute__((address_space(3))) void*)lds,
                                   16, 0, 0);
}
__device__ __forceinline__ ushort_t f2bf(float f) {
  uint32 u = __float_as_uint(f);
  u += 0x7FFFu + ((u >> 16) & 1u);   // round-to-nearest-even
  return (ushort_t)(u >> 16);
}
__device__ __forceinline__ float bf2f(ushort_t b) {
  return __uint_as_float(((uint32)b) << 16);
}
// value from lane^1 via DPP quad_perm [1,0,3,2] (VALU, no LDS)
__device__ __forceinline__ float dpp_xor1(float v) {
  return __int_as_float(__builtin_amdgcn_update_dpp(
      0, __float_as_int(v), 0xB1, 0xf, 0xf, true));
}
#define DPP_MAX(t, ctrl) \
  t = fmaxf(t, __int_as_float(__builtin_amdgcn_update_dpp( \
      0, __float_as_int(t), (ctrl), 0xf, 0xf, true)))
#define DPP_ADD(t, ctrl) \
  t += __int_as_float(__builtin_amdgcn_update_dpp( \
      0, __float_as_int(t), (ctrl), 0xf, 0xf, true))
__device__ __forceinline__ float rowmax16(float t) {
  DPP_MAX(t, 0xB1);   // xor 1
  DPP_MAX(t, 0x4E);   // xor 2
  t = fmaxf(t, __int_as_float(__builtin_amdgcn_ds_swizzle(
      __float_as_int(t), 0x101F)));                  // xor 4
  DPP_MAX(t, 0x128);  // row_ror:8 -> xor 8 (halves uniform after xor1/2/4)
  return t;
}
__device__ __forceinline__ float rowsum16(float t) {
  DPP_ADD(t, 0xB1);
  DPP_ADD(t, 0x4E);
  t += __int_as_float(__builtin_amdgcn_ds_swizzle(__float_as_int(t), 0x101F));
  DPP_ADD(t, 0x128);
  return t;
}

// ---------------------------------------------------------------------------
// Merged preprocessing: [0,4096) cast x->bf16; [4096,8192) transpose W;
// [8192,8448) adapter projections (atomic, 256-block layout as before).
__global__ __launch_bounds__(256) void prep_kernel(
    const float* __restrict__ x, ushort_t* __restrict__ Xb,
    const float* __restrict__ w0, const float* __restrict__ w1,
    const float* __restrict__ w2, const float* __restrict__ w3,
    ushort_t* __restrict__ WtBase,
    const float* __restrict__ adapter,
    float* __restrict__ ak, float* __restrict__ av) {
  __shared__ float L[64][65];
  const int bid = (int)blockIdx.x;
  const int t = (int)threadIdx.x;

  if (bid < 4096) {
    // ---- cast x (fp32) -> bf16, 8 elements/thread ----
    size_t i = ((size_t)bid * 256 + t) * 8;
    float4 a = *(const float4*)(x + i);
    float4 b = *(const float4*)(x + i + 4);
    uint4 o;
    o.x = (uint32)f2bf(a.x) | ((uint32)f2bf(a.y) << 16);
    o.y = (uint32)f2bf(a.z) | ((uint32)f2bf(a.w) << 16);
    o.z = (uint32)f2bf(b.x) | ((uint32)f2bf(b.y) << 16);
    o.w = (uint32)f2bf(b.z) | ((uint32)f2bf(b.w) << 16);
    *(uint4*)(Xb + i) = o;
    return;
  }
  if (bid < 8192) {
    // ---- W[k][n] fp32 -> Wt[n][k] bf16 (64x64 tiles) ----
    int c = bid - 4096;
    const int z = c >> 10, rem = c & 1023;
    const int bx = rem & 31, by = rem >> 5;
    const float* W = (z == 0) ? w0 : (z == 1) ? w1 : (z == 2) ? w2 : w3;
    ushort_t* Wt = WtBase + (size_t)z * 4194304;  // 2048*2048
    int tc = t & 63, tr = t >> 6;
    int k0 = bx * 64, n0 = by * 64;
    for (int i = 0; i < 16; ++i) {
      int r = i * 4 + tr;
      L[r][tc] = W[(size_t)(k0 + r) * 2048 + n0 + tc];
    }
    __syncthreads();
    int tr8 = t >> 5, tc2 = t & 31;
    for (int i = 0; i < 8; ++i) {
      int r = i * 8 + tr8;
      uint32 pk = (uint32)f2bf(L[2 * tc2][r]) | ((uint32)f2bf(L[2 * tc2 + 1][r]) << 16);
      *(uint32*)(Wt + (size_t)(n0 + r) * 2048 + k0 + 2 * tc2) = pk;
    }
    return;
  }
  {
    // ---- adapter: ak/av[l][n] = sum_k adapter[l][k] * W[k][n] ----
    int c = bid - 8192;               // [0,256)
    const int z = c >> 7;             // 0=wk, 1=wv
    const int ky = (c >> 3) & 15;     // k-chunk
    const int xx = c & 7;             // n-chunk
    const float* W = z ? w2 : w1;     // wv : wk
    float* out = z ? av : ak;
    float (*As)[128] = (float(*)[128])L;
    int k0 = ky * 128;
    for (int i = t; i < 1280; i += 256)
      As[i >> 7][i & 127] = adapter[(size_t)(i >> 7) * 2048 + k0 + (i & 127)];
    __syncthreads();
    int n = xx * 256 + t;
    float acc[10];
#pragma unroll
    for (int l = 0; l < 10; ++l) acc[l] = 0.f;
    for (int kk = 0; kk < 128; ++kk) {
      float wv_ = W[(size_t)(k0 + kk) * 2048 + n];
#pragma unroll
      for (int l = 0; l < 10; ++l) acc[l] += As[l][kk] * wv_;
    }
#pragma unroll
    for (int l = 0; l < 10; ++l) atomicAdd(&out[l * 2048 + n], acc[l]);
  }
}

// ---------------------------------------------------------------------------
// pack ak/av (fp32) into MFMA-fragment-friendly bf16 buffers:
// akb[h][l(16)][d(128)] (l>=10 zero), avb[h][d(128)][l(32)] (l>=10 zero)
__global__ __launch_bounds__(256) void adapter_pack_kernel(
    const float* __restrict__ ak, const float* __restrict__ av,
    ushort_t* __restrict__ akb, ushort_t* __restrict__ avb) {
  int t = blockIdx.x * 256 + threadIdx.x;   // 65536 threads
  if (t < 32768) {
    int h = t >> 11, l = (t >> 7) & 15, d = t & 127;
    akb[t] = (l < 10) ? f2bf(ak[l * 2048 + h * 128 + d]) : (ushort_t)0;
  }
  int h = t >> 12, d = (t >> 5) & 127, l = t & 31;
  avb[t] = (l < 10) ? f2bf(av[l * 2048 + h * 128 + d]) : (ushort_t)0;
}

#define QK_BARX() asm volatile("s_barrier" ::: "memory")
#define QK_LGKM0() asm volatile("s_waitcnt lgkmcnt(0)" ::: "memory")

// ---------------------------------------------------------------------------
// R8's proven pipelined 128x256 K-loop (A and B in LDS).
__device__ __forceinline__ void kloop_128x256(
    char* lds, const ushort_t* __restrict__ A, const ushort_t* __restrict__ Bt,
    size_t bm0, size_t bn0, f32x4 (&acc)[4][4]) {
  const int tid = (int)threadIdx.x;
  const int w = tid >> 6, lane = tid & 63, quad = lane >> 4, l15 = lane & 15;
  const int wr = (w >> 2) * 64, wc = (w & 3) * 64;
  const int nt = 32;
  char* const pA0 = lds;
  char* const pA1 = lds + 16384;
  char* const pB0 = lds + 32768;
  char* const pB1 = lds + 65536;

#define PAT(T) (((T) & 1) ? pA1 : pA0)
#define PBT(T) (((T) & 1) ? pB1 : pB0)
#define SEGL(OP, LDSB, GROW, T)                                                \
  do {                                                                         \
    int rr_ = w * 8 + (lane >> 3);                                             \
    int cl_ = (lane & 7) ^ (rr_ & 7);                                          \
    async16((LDSB) + w * 1024,                                                 \
            (OP) + ((GROW) + (size_t)rr_) * 2048 + (size_t)((T) * 64 + cl_ * 8)); \
  } while (0)
#define ST_A(T)                                                                \
  do { if ((T) < nt) { SEGL(A, PAT(T), bm0, (T));                              \
                       SEGL(A, PAT(T) + 8192, bm0 + 64, (T)); } } while (0)
#define ST_B0(T)                                                               \
  do { if ((T) < nt) SEGL(Bt, PBT(T), bn0, (T)); } while (0)
#define ST_B123(T)                                                             \
  do { if ((T) < nt) { SEGL(Bt, PBT(T) + 8192,  bn0 + 64,  (T));               \
                       SEGL(Bt, PBT(T) + 16384, bn0 + 128, (T));               \
                       SEGL(Bt, PBT(T) + 24576, bn0 + 192, (T)); } } while (0)

  ST_A(0); ST_B0(0); ST_B123(0); ST_B123(1);
  asm volatile("s_waitcnt vmcnt(3)" ::: "memory");
  QK_BARX();

#pragma unroll 2
  for (int t = 0; t < nt; ++t) {
    const char* pA = PAT(t);
    const char* pB = PBT(t);
    bf16x8 bfv[4][2];
#pragma unroll
    for (int j = 0; j < 4; ++j) {
      int brow = wc + j * 16 + l15;
#pragma unroll
      for (int ks = 0; ks < 2; ++ks)
        bfv[j][ks] = *(const bf16x8*)(pB + brow * 128 +
                                      (((ks * 4 + quad) ^ (brow & 7)) * 16));
    }
#pragma unroll
    for (int ph = 0; ph < 2; ++ph) {
      bf16x8 af[2][2];
#pragma unroll
      for (int ii = 0; ii < 2; ++ii) {
        int arow = wr + (ph * 2 + ii) * 16 + l15;
#pragma unroll
        for (int ks = 0; ks < 2; ++ks)
          af[ii][ks] = *(const bf16x8*)(pA + arow * 128 +
                                        (((ks * 4 + quad) ^ (arow & 7)) * 16));
      }
      if (ph == 0) { ST_A(t + 1); ST_B0(t + 1); }
      else         { ST_B123(t + 2); }
      QK_BARX();
      QK_LGKM0();
      __builtin_amdgcn_s_setprio(1);
#pragma unroll
      for (int ks = 0; ks < 2; ++ks)
#pragma unroll
        for (int ii = 0; ii < 2; ++ii)
#pragma unroll
          for (int j = 0; j < 4; ++j)
            acc[ph * 2 + ii][j] = __builtin_amdgcn_mfma_f32_16x16x32_bf16(
                af[ii][ks], bfv[j][ks], acc[ph * 2 + ii][j], 0, 0, 0);
      __builtin_amdgcn_s_setprio(0);
      if (ph == 1) {
        if (t == nt - 2) asm volatile("s_waitcnt vmcnt(0)" ::: "memory");
        else             asm volatile("s_waitcnt vmcnt(3)" ::: "memory");
      }
      QK_BARX();
    }
  }
#undef PAT
#undef PBT
#undef SEGL
#undef ST_A
#undef ST_B0
#undef ST_B123
}

// ---------------------------------------------------------------------------
// Fused QKV GEMM: C[4096,6144] = Xb[4096,2048] x WtQKV[6144,2048]^T.
// Grid 768 (32 M x 24 N) = exactly 3 rounds of 256 CUs.
__global__ __launch_bounds__(512, 2) void gemm_qkv128_kernel(
    const ushort_t* __restrict__ A, const ushort_t* __restrict__ Bt,
    ushort_t* __restrict__ outQ, ushort_t* __restrict__ outK,
    ushort_t* __restrict__ Vt,
    const float* __restrict__ fc, const float* __restrict__ fs) {
  __shared__ char lds[98304];
  const int tid = (int)threadIdx.x;
  const int w = tid >> 6, lane = tid & 63, quad = lane >> 4, l15 = lane & 15;
  const int wr = (w >> 2) * 64, wc = (w & 3) * 64;

  const int wg = ((int)blockIdx.x & 7) * 96 + ((int)blockIdx.x >> 3);
  const size_t bm0 = (size_t)(wg & 31) * 128;
  const size_t bn0 = (size_t)(wg >> 5) * 256;

  f32x4 acc[4][4];
  f32x4 z4 = {0.f, 0.f, 0.f, 0.f};
#pragma unroll
  for (int i = 0; i < 4; ++i)
#pragma unroll
    for (int j = 0; j < 4; ++j) acc[i][j] = z4;

  kloop_128x256(lds, A, Bt, bm0, bn0, acc);

  const int seg = (int)(bn0 >> 11);   // 0=Q, 1=K, 2=V
  if (seg < 2) {
    ushort_t* ob = seg ? outK : outQ;
#pragma unroll
    for (int i = 0; i < 4; ++i)
#pragma unroll
      for (int r = 0; r < 4; ++r) {
        size_t m = bm0 + wr + i * 16 + quad * 4 + r;
        int s = (int)(m & 2047);
#pragma unroll
        for (int j = 0; j < 4; ++j) {
          size_t n = (bn0 + wc + j * 16 + l15) & 2047;
          float v = acc[i][j][r];
          float v2 = dpp_xor1(v);             // RoPE pair partner (col n^1)
          int fi = ((int)n & 127) >> 1;
          float cosv = fc[s * 64 + fi];
          float sinv = fs[s * 64 + fi];
          v = (lane & 1) ? (v2 * sinv + v * cosv) : (v * cosv - v2 * sinv);
          ob[m * 2048 + n] = f2bf(v);
        }
      }
  } else {
    // V segment: per-wave 64(n) x 64(m) transpose patch through LDS.
    char* T = lds + w * 8192;
#pragma unroll
    for (int i = 0; i < 4; ++i)
#pragma unroll
      for (int j = 0; j < 4; ++j) {
        int nn = j * 16 + l15;
        int md0 = i * 8 + quad * 2;
        uint32 p01 = (uint32)f2bf(acc[i][j][0]) | ((uint32)f2bf(acc[i][j][1]) << 16);
        uint32 p23 = (uint32)f2bf(acc[i][j][2]) | ((uint32)f2bf(acc[i][j][3]) << 16);
        *(uint32*)(T + nn * 128 + ((md0 ^ (nn & 31)) * 4)) = p01;
        *(uint32*)(T + nn * 128 + (((md0 + 1) ^ (nn & 31)) * 4)) = p23;
      }
    const int b = (int)(bm0 >> 11);
    const int s0 = (int)(bm0 & 2047) + wr;
    const int n2 = (int)(bn0 & 2047) + wc;
#pragma unroll
    for (int it = 0; it < 32; ++it) {
      int row = it * 2 + (lane >> 5);
      int pp = lane & 31;
      uint32 dv = *(const uint32*)(T + row * 128 + pp * 4);
      int md = pp ^ (row & 31);
      int nloc = n2 + row;
      size_t bh = (size_t)b * 16 + (nloc >> 7);
      *(uint32*)(Vt + (bh * 128 + (size_t)(nloc & 127)) * 2048 + s0 + 2 * md) = dv;
    }
  }
}

// ---------------------------------------------------------------------------
// Output projection: out[4096,2048] fp32 = Ob x WtO^T. Grid 256 = 1 round.
__global__ __launch_bounds__(512, 2) void gemm_wo_kernel(
    const ushort_t* __restrict__ A, const ushort_t* __restrict__ Bt,
    float* __restrict__ out) {
  __shared__ char lds[98304];
  const int tid = (int)threadIdx.x;
  const int w = tid >> 6, lane = tid & 63, quad = lane >> 4, l15 = lane & 15;
  const int wr = (w >> 2) * 64, wc = (w & 3) * 64;

  const int wg = ((int)blockIdx.x & 7) * 32 + ((int)blockIdx.x >> 3);
  const size_t bm0 = (size_t)(wg & 31) * 128;
  const size_t bn0 = (size_t)(wg >> 5) * 256;

  f32x4 acc[4][4];
  f32x4 z4 = {0.f, 0.f, 0.f, 0.f};
#pragma unroll
  for (int i = 0; i < 4; ++i)
#pragma unroll
    for (int j = 0; j < 4; ++j) acc[i][j] = z4;

  kloop_128x256(lds, A, Bt, bm0, bn0, acc);

#pragma unroll
  for (int i = 0; i < 4; ++i)
#pragma unroll
    for (int r = 0; r < 4; ++r) {
      size_t m = bm0 + wr + i * 16 + quad * 4 + r;
#pragma unroll
      for (int j = 0; j < 4; ++j) {
        size_t n = bn0 + wc + j * 16 + l15;
        out[m * 2048 + n] = acc[i][j][r];
      }
    }
}

// ---------------------------------------------------------------------------
// Flash attention, causal, + fused adapter attention.
// R13: K/V double-buffered (stage kt+1 during compute of kt; vmcnt(8) keeps
// the 8 prefetch loads in flight across the barrier; vmcnt(0) only on the
// last tile). 128q/block (4 waves x 32 rows), defer-max THR=8, dpp+cvt_pk
// packed P-store. LDS 80KB; grid 512 => 2 blocks/CU (unchanged residency).
__global__ __launch_bounds__(256) void flash_kernel(
    const ushort_t* __restrict__ Qb, const ushort_t* __restrict__ Kb,
    const ushort_t* __restrict__ Vt, const ushort_t* __restrict__ akb,
    const ushort_t* __restrict__ avb, const float* __restrict__ gate,
    ushort_t* __restrict__ Ob) {
  __shared__ char ldsK[32768];   // 2 x (64 tok x 256B), chunk swz ^(row&15)
  __shared__ char ldsV[32768];   // 2 x (128 d x 128B), chunk swz ^(dr&7)
  __shared__ char ldsP[16384];   // loop: P 128q x 128B swz; epilogue: pa[128][40]
  const int tid = threadIdx.x;
  const int w = tid >> 6, lane = tid & 63, quad = lane >> 4, l15 = lane & 15;
  const int idx = blockIdx.x;
  const int p = idx >> 8, c = idx & 255;
  const int u = c >> 4, vv = c & 15;
  const int qt = p ? (15 - u) : u;
  const int hb = (p << 4) | vv;
  const int h = hb >> 1, b = hb & 1;
  const float scale = 0.08838834764831845f;  // 1/sqrt(128)

  bf16x8 ones;
#pragma unroll
  for (int j = 0; j < 8; ++j) ones[j] = (short)0x3F80;

  // Q fragments in registers: 2 m-tiles x 4 d-steps (wave rows w*32..+31)
  bf16x8 qf[2][4];
#pragma unroll
  for (int mt = 0; mt < 2; ++mt) {
    size_t qrow = (size_t)qt * 128 + w * 32 + mt * 16 + l15;
    const ushort_t* base = Qb + ((size_t)b * 2048 + qrow) * 2048 + h * 128 + quad * 8;
#pragma unroll
    for (int ds = 0; ds < 4; ++ds) qf[mt][ds] = *(const bf16x8*)(base + ds * 32);
  }

  f32x4 zero4 = {0.f, 0.f, 0.f, 0.f};
  f32x4 oacc[2][8];
  f32x4 osum[2];
  float mrow[2][4];
#pragma unroll
  for (int mt = 0; mt < 2; ++mt) {
#pragma unroll
    for (int n8 = 0; n8 < 8; ++n8) oacc[mt][n8] = zero4;
    osum[mt] = zero4;
#pragma unroll
    for (int r = 0; r < 4; ++r) mrow[mt][r] = -1e30f;
  }

// stage K/V tile KT into buffer BUF (8 async16/thread)
#define STAGE_KV(KT, BUF)                                                      \
  do {                                                                         \
    char* bK_ = ldsK + (BUF) * 16384;                                          \
    char* bV_ = ldsV + (BUF) * 16384;                                          \
    _Pragma("unroll") for (int ii = 0; ii < 4; ++ii) {                         \
      int r0 = w * 16 + ii * 4;                                                \
      int row = r0 + (lane >> 4);                                              \
      int cl = (lane & 15) ^ (row & 15);                                       \
      async16(bK_ + r0 * 256,                                                  \
              Kb + ((size_t)b * 2048 + (KT) * 64 + row) * 2048 + h * 128 + cl * 8); \
    }                                                                          \
    _Pragma("unroll") for (int ii = 0; ii < 4; ++ii) {                         \
      int d0 = w * 32 + ii * 8;                                                \
      int dr = d0 + (lane >> 3);                                               \
      int cl = (lane & 7) ^ (dr & 7);                                          \
      async16(bV_ + d0 * 128,                                                  \
              Vt + ((size_t)(b * 16 + h) * 128 + dr) * 2048 + (KT) * 64 + cl * 8); \
    }                                                                          \
  } while (0)

  const int ktmax = 2 * qt + 1;
  STAGE_KV(0, 0);
  for (int kt = 0; kt <= ktmax; ++kt) {
    const int cb = kt & 1;
    if (kt < ktmax) {
      STAGE_KV(kt + 1, cb ^ 1);
      asm volatile("s_waitcnt vmcnt(8)" ::: "memory");   // kt's 8 loads done
    } else {
      asm volatile("s_waitcnt vmcnt(0)" ::: "memory");
    }
    QK_BARX();
    const char* bK = ldsK + cb * 16384;
    const char* bV = ldsV + cb * 16384;

    // S = Q K^T
    f32x4 sacc[2][4];
#pragma unroll
    for (int mt = 0; mt < 2; ++mt)
#pragma unroll
      for (int nt = 0; nt < 4; ++nt) sacc[mt][nt] = zero4;
#pragma unroll
    for (int ds = 0; ds < 4; ++ds) {
      bf16x8 kf[4];
      int ch = ds * 4 + quad;
#pragma unroll
      for (int nt = 0; nt < 4; ++nt) {
        int row = nt * 16 + l15;
        kf[nt] = *(const bf16x8*)(bK + row * 256 + ((ch ^ (row & 15)) * 16));
      }
#pragma unroll
      for (int mt = 0; mt < 2; ++mt)
#pragma unroll
        for (int nt = 0; nt < 4; ++nt)
          sacc[mt][nt] = __builtin_amdgcn_mfma_f32_16x16x32_bf16(qf[mt][ds], kf[nt], sacc[mt][nt], 0, 0, 0);
    }

    // online softmax (defer-max, THR=8)
    const bool domask = (kt >= 2 * qt);
    float tmax2[2][4];
    float need = 0.f;
#pragma unroll
    for (int mt = 0; mt < 2; ++mt) {
      float tmax[4] = {-1e30f, -1e30f, -1e30f, -1e30f};
      const int qbase = qt * 128 + w * 32 + mt * 16 + quad * 4;
#pragma unroll
      for (int nt = 0; nt < 4; ++nt) {
        int kg = kt * 64 + nt * 16 + l15;
#pragma unroll
        for (int r = 0; r < 4; ++r) {
          float s = sacc[mt][nt][r] * scale;
          if (domask && kg > qbase + r) s = -1e30f;
          sacc[mt][nt][r] = s;
          tmax[r] = fmaxf(tmax[r], s);
        }
      }
#pragma unroll
      for (int r = 0; r < 4; ++r) {
        tmax2[mt][r] = rowmax16(tmax[r]);
        need = fmaxf(need, tmax2[mt][r] - mrow[mt][r]);
      }
    }
    if (__any(need > 8.0f)) {
#pragma unroll
      for (int mt = 0; mt < 2; ++mt) {
        float alpha[4];
#pragma unroll
        for (int r = 0; r < 4; ++r) {
          float mnew = fmaxf(mrow[mt][r], tmax2[mt][r]);
          alpha[r] = __expf(mrow[mt][r] - mnew);
          osum[mt][r] *= alpha[r];
          mrow[mt][r] = mnew;
        }
#pragma unroll
        for (int n8 = 0; n8 < 8; ++n8)
#pragma unroll
          for (int r = 0; r < 4; ++r) oacc[mt][n8][r] *= alpha[r];
      }
    }
    // P = exp(s - mrow); pack col pairs (l, l^1) via dpp + cvt_pk, even lanes
    // store dwords into swizzled ldsP.
#pragma unroll
    for (int mt = 0; mt < 2; ++mt) {
      uint32 pk[4][4];
#pragma unroll
      for (int nt = 0; nt < 4; ++nt)
#pragma unroll
        for (int r = 0; r < 4; ++r) {
          float pv = __expf(sacc[mt][nt][r] - mrow[mt][r]);
          float pn = dpp_xor1(pv);
          uint32 d_;
          asm volatile("v_cvt_pk_bf16_f32 %0, %1, %2" : "=v"(d_) : "v"(pv), "v"(pn));
          pk[nt][r] = d_;
        }
      if (!(lane & 1)) {
#pragma unroll
        for (int nt = 0; nt < 4; ++nt)
#pragma unroll
          for (int r = 0; r < 4; ++r) {
            int col = nt * 16 + l15;   // even
            int prow = w * 32 + mt * 16 + quad * 4 + r;
            *(uint32*)(ldsP + prow * 128 + (((col >> 3) ^ (prow & 7)) * 16) + (col & 7) * 2) = pk[nt][r];
          }
      }
    }

    // O += P V ; osum += P 1
#pragma unroll
    for (int ks = 0; ks < 2; ++ks) {
      int ch = ks * 4 + quad;
      bf16x8 pf[2];
#pragma unroll
      for (int mt = 0; mt < 2; ++mt) {
        int prow = w * 32 + mt * 16 + l15;
        pf[mt] = *(const bf16x8*)(ldsP + prow * 128 + ((ch ^ (prow & 7)) * 16));
      }
#pragma unroll
      for (int mt = 0; mt < 2; ++mt)
        osum[mt] = __builtin_amdgcn_mfma_f32_16x16x32_bf16(pf[mt], ones, osum[mt], 0, 0, 0);
#pragma unroll
      for (int n8 = 0; n8 < 8; ++n8) {
        int dr = n8 * 16 + l15;
        bf16x8 vf = *(const bf16x8*)(bV + dr * 128 + ((ch ^ (dr & 7)) * 16));
#pragma unroll
        for (int mt = 0; mt < 2; ++mt)
          oacc[mt][n8] = __builtin_amdgcn_mfma_f32_16x16x32_bf16(pf[mt], vf, oacc[mt][n8], 0, 0, 0);
      }
    }
    QK_BARX();
  }
#undef STAGE_KV

  // ---------------- fused adapter epilogue ----------------
  const float g = gate[h];
  {
    int row = w * 32 + (lane >> 1);
    int koff = 16 + (lane & 1) * 8;
    *(uint4*)(ldsP + row * 80 + koff * 2) = make_uint4(0, 0, 0, 0);
  }
  f32x4 sa[2] = {zero4, zero4};
#pragma unroll
  for (int ds = 0; ds < 4; ++ds) {
    bf16x8 kfa = *(const bf16x8*)(akb + ((size_t)h * 16 + l15) * 128 + ds * 32 + quad * 8);
#pragma unroll
    for (int mt = 0; mt < 2; ++mt)
      sa[mt] = __builtin_amdgcn_mfma_f32_16x16x32_bf16(qf[mt][ds], kfa, sa[mt], 0, 0, 0);
  }
#pragma unroll
  for (int mt = 0; mt < 2; ++mt) {
#pragma unroll
    for (int r = 0; r < 4; ++r) {
      float s = sa[mt][r] * scale;
      if (l15 >= 10) s = -1e30f;
      float mx = rowmax16(s);
      float e = __expf(s - mx);
      float sum = rowsum16(e);
      float pv = g * e / sum;
      int row = w * 32 + mt * 16 + quad * 4 + r;
      *(ushort_t*)(ldsP + row * 80 + l15 * 2) = f2bf(pv);
    }
  }
  bf16x8 paf[2];
#pragma unroll
  for (int mt = 0; mt < 2; ++mt)
    paf[mt] = *(const bf16x8*)(ldsP + (w * 32 + mt * 16 + l15) * 80 + quad * 16);

  // normalize main attention
#pragma unroll
  for (int mt = 0; mt < 2; ++mt) {
    float rl[4];
#pragma unroll
    for (int r = 0; r < 4; ++r) rl[r] = 1.f / osum[mt][r];
#pragma unroll
    for (int n8 = 0; n8 < 8; ++n8)
#pragma unroll
      for (int r = 0; r < 4; ++r) oacc[mt][n8][r] *= rl[r];
  }
  // += pa @ avb ; store bf16
#pragma unroll
  for (int n8 = 0; n8 < 8; ++n8) {
    bf16x8 avf = *(const bf16x8*)(avb + ((size_t)h * 128 + n8 * 16 + l15) * 32 + quad * 8);
#pragma unroll
    for (int mt = 0; mt < 2; ++mt)
      oacc[mt][n8] = __builtin_amdgcn_mfma_f32_16x16x32_bf16(paf[mt], avf, oacc[mt][n8], 0, 0, 0);
  }
#pragma unroll
  for (int mt = 0; mt < 2; ++mt) {
    size_t qb0 = (size_t)qt * 128 + w * 32 + mt * 16 + quad * 4;
#pragma unroll
    for (int n8 = 0; n8 < 8; ++n8) {
      size_t col = (size_t)h * 128 + n8 * 16 + l15;
#pragma unroll
      for (int r = 0; r < 4; ++r)
        Ob[((size_t)b * 2048 + qb0 + r) * 2048 + col] = f2bf(oacc[mt][n8][r]);
    }
  }
}

// ---------------------------------------------------------------------------
extern "C" void kernel_launch(void* const* d_in, const int* in_sizes, int n_in,
                              void* d_out, int out_size, void* d_ws, size_t ws_size,
                              hipStream_t stream) {
  (void)in_sizes; (void)n_in; (void)out_size; (void)ws_size;
  const float* x       = (const float*)d_in[0];
  const float* wq      = (const float*)d_in[1];
  const float* wk      = (const float*)d_in[2];
  const float* wv      = (const float*)d_in[3];
  const float* wo      = (const float*)d_in[4];
  const float* adapter = (const float*)d_in[5];
  const float* gate    = (const float*)d_in[6];
  const float* fc      = (const float*)d_in[7];
  const float* fs      = (const float*)d_in[8];

  char* ws = (char*)d_ws;
  ushort_t* Xb   = (ushort_t*)(ws + 0);           // 16 MB (reused as Ob)
  ushort_t* WtQ  = (ushort_t*)(ws + 16777216);    // 8 MB x4 contiguous
  ushort_t* WtO  = (ushort_t*)(ws + 41943040);
  ushort_t* Qb   = (ushort_t*)(ws + 50331648);    // 16 MB
  ushort_t* Kb   = (ushort_t*)(ws + 67108864);    // 16 MB
  ushort_t* Vt   = (ushort_t*)(ws + 83886080);    // 16 MB
  float*    ak   = (float*)   (ws + 100663296);   // 80 KB
  float*    av   = (float*)   (ws + 100745216);   // 80 KB
  ushort_t* akb  = (ushort_t*)(ws + 100827136);   // 64 KB
  ushort_t* avb  = (ushort_t*)(ws + 100892672);   // 128 KB
  ushort_t* Ob   = Xb;

  hipMemsetAsync(ak, 0, 163840, stream);
  prep_kernel<<<8448, 256, 0, stream>>>(x, Xb, wq, wk, wv, wo, WtQ,
                                        adapter, ak, av);
  adapter_pack_kernel<<<256, 256, 0, stream>>>(ak, av, akb, avb);
  gemm_qkv128_kernel<<<dim3(768), 512, 0, stream>>>(Xb, WtQ, Qb, Kb, Vt, fc, fs);
  flash_kernel<<<dim3(512), 256, 0, stream>>>(Qb, Kb, Vt, akb, avb, gate, Ob);
  gemm_wo_kernel<<<dim3(256), 512, 0, stream>>>(Ob, WtO, (float*)d_out);
}